// Round 9
// baseline (138.651 us; speedup 1.0000x reference)
//
#include <hip/hip_runtime.h>
#include <math.h>

#define NSV 512

// ws layout (float offsets, all even)
#define OFF_SV0   0
#define OFF_SVA   16384
#define OFF_SVB   81920
#define OFF_EXPV  147456
#define OFF_SM0   147584
#define OFF_PME0  147840
#define OFF_PME1  148864
#define OFF_PME2  165248
#define OFF_PME3  181632
#define OFF_PSA   198016
#define OFF_PSB   206208
#define OFF_ORB   214400

// ---------------------------------------------------------------------------
// Persistent-kernel infra. Cross-block ws data: RELAXED+AGENT atomics
// (per-access coherent at LLC, no cache-wide invalidates). R8 lesson: scalar
// atomics are ~700cy each and un-vectorized -> use 64-bit atomics (float2)
// everywhere. Weights/biases = read-only inputs -> plain cached loads.
// ---------------------------------------------------------------------------
__device__ unsigned g_bar  = 0;
__device__ unsigned g_exit = 0;

__device__ __forceinline__ float gload(const float* p) {
    return __hip_atomic_load(p, __ATOMIC_RELAXED, __HIP_MEMORY_SCOPE_AGENT);
}
__device__ __forceinline__ void gstore(float* p, float v) {
    __hip_atomic_store(p, v, __ATOMIC_RELAXED, __HIP_MEMORY_SCOPE_AGENT);
}
__device__ __forceinline__ float2 gload2(const float* p) {
    unsigned long long u = __hip_atomic_load((const unsigned long long*)p,
                            __ATOMIC_RELAXED, __HIP_MEMORY_SCOPE_AGENT);
    union { unsigned long long u; float2 f; } c; c.u = u; return c.f;
}
__device__ __forceinline__ void gstore2(float* p, float a, float b) {
    union { float2 f; unsigned long long u; } c; c.f = make_float2(a, b);
    __hip_atomic_store((unsigned long long*)p, c.u,
                       __ATOMIC_RELAXED, __HIP_MEMORY_SCOPE_AGENT);
}

__device__ __forceinline__ void gsync(unsigned target) {
    __syncthreads();                     // drains vmcnt for every wave
    if (threadIdx.x == 0) {
        atomicAdd(&g_bar, 1u);
        while (__hip_atomic_load(&g_bar, __ATOMIC_RELAXED,
                                 __HIP_MEMORY_SCOPE_AGENT) < target)
            __builtin_amdgcn_s_sleep(2);
    }
    __syncthreads();
}

// ---------------------------------------------------------------------------
// P0a: pair-stream chain, one block per column j, entirely in LDS.
// Emits pme0..pme3, sv0 row j, expv[j]. p never touches global memory.
// ---------------------------------------------------------------------------
__device__ void pchain_role(int j, const float* __restrict__ r,
                            const float* __restrict__ apos,
                            const float* __restrict__ W0w, const float* __restrict__ W0b,
                            const float* __restrict__ W1w, const float* __restrict__ W1b,
                            const float* __restrict__ W2w, const float* __restrict__ W2b,
                            float* __restrict__ sv0, float* __restrict__ expv,
                            float* __restrict__ pme0, float* __restrict__ pme1,
                            float* __restrict__ pme2, float* __restrict__ pme3,
                            float* sh)
{
    float* rL   = sh;            // 384
    float* W0l  = sh + 384;      // 256
    float* shex = sh + 640;      // 32
    float* p0c  = sh + 672;      // 512
    float* PA   = sh + 1184;     // 128*68
    float* Wbuf = sh + 9888;     // 4096
    const int t = threadIdx.x;
    const int i  = t >> 2;
    const int o0 = (t & 3) * 16;

    if (t < 384) rL[t] = r[t];
    for (int idx = t; idx < 4096; idx += 512) Wbuf[idx] = W1w[idx];
    if (t < 256) W0l[t] = W0w[t];
    __syncthreads();

    const float rjx = rL[j*3+0], rjy = rL[j*3+1], rjz = rL[j*3+2];
    if (t < 128) {
        const int ii = t;
        float dx = rjx - rL[ii*3+0], dy = rjy - rL[ii*3+1], dz = rjz - rL[ii*3+2];
        float len = (ii == j) ? 0.f : sqrtf(dx*dx + dy*dy + dz*dz);
        p0c[ii*4+0]=dx; p0c[ii*4+1]=dy; p0c[ii*4+2]=dz; p0c[ii*4+3]=len;
    } else if (t < 160) {
        const int k = t - 128;
        float dx = rjx - apos[k*3+0], dy = rjy - apos[k*3+1], dz = rjz - apos[k*3+2];
        float len = sqrtf(dx*dx + dy*dy + dz*dz);
        gstore2(&sv0[(size_t)j*128 + k*4],     dx, dy);
        gstore2(&sv0[(size_t)j*128 + k*4 + 2], dz, len);
        shex[k] = expf(-len);
    }
    __syncthreads();

    {   // layer0: PA[i][o] = tanh(p0c[i] @ W0 + b0)
        const float x0=p0c[i*4+0], x1=p0c[i*4+1], x2=p0c[i*4+2], x3=p0c[i*4+3];
        #pragma unroll
        for (int k = 0; k < 16; ++k) {
            const int o = o0 + k;
            float acc = W0b[o];
            acc = fmaf(x0, W0l[o],     acc);
            acc = fmaf(x1, W0l[64+o],  acc);
            acc = fmaf(x2, W0l[128+o], acc);
            acc = fmaf(x3, W0l[192+o], acc);
            PA[i*68+o] = tanhf(acc);
        }
    }
    if (t < 4) {
        const int spin = t >> 1, c0 = (t & 1) * 2;
        float s0 = 0.f, s1 = 0.f;
        #pragma unroll 8
        for (int k = 0; k < 64; ++k) {
            s0 += p0c[(spin*64+k)*4 + c0];
            s1 += p0c[(spin*64+k)*4 + c0 + 1];
        }
        gstore2(&pme0[j*8 + spin*4 + c0], s0*0.015625f, s1*0.015625f);
    }
    if (t == 8) {
        float s = 0.f;
        #pragma unroll 8
        for (int k = 0; k < 32; ++k) s += shex[k];
        gstore(&expv[j], s);
    }
    __syncthreads();

    // pme1 + layer1
    if (t < 64) {
        const int spin = t >> 5, c0 = (t & 31) * 2;
        float s0 = 0.f, s1 = 0.f;
        #pragma unroll 8
        for (int k = 0; k < 64; ++k) {
            s0 += PA[(spin*64+k)*68 + c0];
            s1 += PA[(spin*64+k)*68 + c0 + 1];
        }
        gstore2(&pme1[j*128 + spin*64 + c0], s0*0.015625f, s1*0.015625f);
    }
    float acc[16], res[16];
    const float* pa = PA + i*68;
    {
        #pragma unroll
        for (int k = 0; k < 16; ++k) acc[k] = W1b[o0+k];
        #pragma unroll 4
        for (int c = 0; c < 64; ++c) {
            const float av = pa[c];
            const float* wr = Wbuf + c*64 + o0;
            float4 wa = *reinterpret_cast<const float4*>(wr);
            float4 wb = *reinterpret_cast<const float4*>(wr+4);
            float4 wc = *reinterpret_cast<const float4*>(wr+8);
            float4 wd = *reinterpret_cast<const float4*>(wr+12);
            acc[0] =fmaf(av,wa.x,acc[0]);  acc[1] =fmaf(av,wa.y,acc[1]);
            acc[2] =fmaf(av,wa.z,acc[2]);  acc[3] =fmaf(av,wa.w,acc[3]);
            acc[4] =fmaf(av,wb.x,acc[4]);  acc[5] =fmaf(av,wb.y,acc[5]);
            acc[6] =fmaf(av,wb.z,acc[6]);  acc[7] =fmaf(av,wb.w,acc[7]);
            acc[8] =fmaf(av,wc.x,acc[8]);  acc[9] =fmaf(av,wc.y,acc[9]);
            acc[10]=fmaf(av,wc.z,acc[10]); acc[11]=fmaf(av,wc.w,acc[11]);
            acc[12]=fmaf(av,wd.x,acc[12]); acc[13]=fmaf(av,wd.y,acc[13]);
            acc[14]=fmaf(av,wd.z,acc[14]); acc[15]=fmaf(av,wd.w,acc[15]);
        }
        #pragma unroll
        for (int k = 0; k < 16; ++k) res[k] = pa[o0+k];
    }
    __syncthreads();
    #pragma unroll
    for (int k = 0; k < 16; ++k) PA[i*68+o0+k] = tanhf(acc[k]) + res[k];
    __syncthreads();

    // pme2 + restage W2
    if (t < 64) {
        const int spin = t >> 5, c0 = (t & 31) * 2;
        float s0 = 0.f, s1 = 0.f;
        #pragma unroll 8
        for (int k = 0; k < 64; ++k) {
            s0 += PA[(spin*64+k)*68 + c0];
            s1 += PA[(spin*64+k)*68 + c0 + 1];
        }
        gstore2(&pme2[j*128 + spin*64 + c0], s0*0.015625f, s1*0.015625f);
    }
    for (int idx = t; idx < 4096; idx += 512) Wbuf[idx] = W2w[idx];
    __syncthreads();

    {   // layer2
        #pragma unroll
        for (int k = 0; k < 16; ++k) acc[k] = W2b[o0+k];
        #pragma unroll 4
        for (int c = 0; c < 64; ++c) {
            const float av = pa[c];
            const float* wr = Wbuf + c*64 + o0;
            float4 wa = *reinterpret_cast<const float4*>(wr);
            float4 wb = *reinterpret_cast<const float4*>(wr+4);
            float4 wc = *reinterpret_cast<const float4*>(wr+8);
            float4 wd = *reinterpret_cast<const float4*>(wr+12);
            acc[0] =fmaf(av,wa.x,acc[0]);  acc[1] =fmaf(av,wa.y,acc[1]);
            acc[2] =fmaf(av,wa.z,acc[2]);  acc[3] =fmaf(av,wa.w,acc[3]);
            acc[4] =fmaf(av,wb.x,acc[4]);  acc[5] =fmaf(av,wb.y,acc[5]);
            acc[6] =fmaf(av,wb.z,acc[6]);  acc[7] =fmaf(av,wb.w,acc[7]);
            acc[8] =fmaf(av,wc.x,acc[8]);  acc[9] =fmaf(av,wc.y,acc[9]);
            acc[10]=fmaf(av,wc.z,acc[10]); acc[11]=fmaf(av,wc.w,acc[11]);
            acc[12]=fmaf(av,wd.x,acc[12]); acc[13]=fmaf(av,wd.y,acc[13]);
            acc[14]=fmaf(av,wd.z,acc[14]); acc[15]=fmaf(av,wd.w,acc[15]);
        }
        #pragma unroll
        for (int k = 0; k < 16; ++k) res[k] = pa[o0+k];
    }
    __syncthreads();
    #pragma unroll
    for (int k = 0; k < 16; ++k) PA[i*68+o0+k] = tanhf(acc[k]) + res[k];
    __syncthreads();

    if (t < 64) {
        const int spin = t >> 5, c0 = (t & 31) * 2;
        float s0 = 0.f, s1 = 0.f;
        #pragma unroll 8
        for (int k = 0; k < 64; ++k) {
            s0 += PA[(spin*64+k)*68 + c0];
            s1 += PA[(spin*64+k)*68 + c0 + 1];
        }
        gstore2(&pme3[j*128 + spin*64 + c0], s0*0.015625f, s1*0.015625f);
    }
}

// ---------------------------------------------------------------------------
// P0b (blocks 128..135): smean0 directly from geometry (no sv0 dependency).
// sm0g[idx], idx = spin*128 + col, col = a_i*4 + d: mean over spin electrons
// of sv0 feature. 32 idx per block, 16 threads each (4 electrons per thread).
// ---------------------------------------------------------------------------
__device__ void smean0_role(int g, const float* __restrict__ r,
                            const float* __restrict__ apos,
                            float* __restrict__ sm0g, float* sh)
{
    const int t = threadIdx.x;
    const int idx = g*32 + (t >> 4);
    const int sub = t & 15;
    const int spin = idx >> 7, col = idx & 127;
    const int a_i = col >> 2, d = col & 3;
    const float ax = apos[a_i*3+0], ay = apos[a_i*3+1], az = apos[a_i*3+2];
    float s = 0.f;
    #pragma unroll
    for (int q = 0; q < 4; ++q) {
        const int e = spin*64 + sub*4 + q;
        float dx = r[e*3+0]-ax, dy = r[e*3+1]-ay, dz = r[e*3+2]-az;
        float len = sqrtf(dx*dx + dy*dy + dz*dz);
        s += (d==0)?dx:(d==1)?dy:(d==2)?dz:len;
    }
    sh[t] = s;
    __syncthreads();
    if (sub == 0) {
        float tot = 0.f;
        #pragma unroll
        for (int q = 0; q < 16; ++q) tot += sh[t + q];
        gstore(&sm0g[idx], tot * 0.015625f);
    }
}

// ---------------------------------------------------------------------------
// P1..P4: s-stream GEMM. 128 blocks, tile 8e x 64o (et=b>>3, ot=b&7).
// One wave per electron, full K. smean: L0 from sm0g, else from psum tiles.
// ---------------------------------------------------------------------------
template<int FS, int FP, bool L0>
__device__ void a2_role(int b, const float* __restrict__ svIn,
                        const float* __restrict__ pmeIn,
                        const float* __restrict__ smSrc,
                        const float* __restrict__ Vw, const float* __restrict__ Vb,
                        float* __restrict__ svOut, float* __restrict__ psumOut,
                        float* sh)
{
    constexpr int KP = 2*FP + FS;         // 136 (L0) or 640
    float* As  = sh;                      // 8*KP
    float* smL = sh + 8*KP;               // 2*FS
    float* red = smL + 2*FS;              // 512
    float* t1L = red + 512;               // 64
    const int t  = threadIdx.x;
    const int et = b >> 3;
    const int e0 = et * 8;
    const int o0 = (b & 7) * 64;
    const int ol = t & 63;
    const int o  = o0 + ol;
    const int wv = t >> 6;                // 0..7

    for (int q = t; q < 8*FP; q += 512) {           // pme pairs
        const int row = q / FP, c0 = (q % FP) * 2;
        float2 v = gload2(&pmeIn[(size_t)(e0+row)*(2*FP) + c0]);
        As[row*KP + c0] = v.x; As[row*KP + c0 + 1] = v.y;
    }
    for (int q = t; q < 4*FS; q += 512) {           // sv pairs
        const int row = q / (FS/2), c0 = (q % (FS/2)) * 2;
        float2 v = gload2(&svIn[(size_t)(e0+row)*FS + c0]);
        As[row*KP + 2*FP + c0] = v.x; As[row*KP + 2*FP + c0 + 1] = v.y;
    }
    if (L0) {
        if (t < FS) {                                // FS=128: 128 pair-loads
            float2 v = gload2(&smSrc[2*t]);
            smL[2*t] = v.x; smL[2*t+1] = v.y;
        }
    } else {
        if (t < FS) {                                // FS=512: pair (2t,2t+1)
            const int c0 = (2*t) & (FS-1);
            const int r0 = (2*t < FS) ? 0 : 8;
            float s0 = 0.f, s1 = 0.f;
            #pragma unroll
            for (int k = 0; k < 8; ++k) {
                float2 v = gload2(&smSrc[(size_t)(r0+k)*NSV + c0]);
                s0 += v.x; s1 += v.y;
            }
            smL[2*t] = s0 * 0.015625f; smL[2*t+1] = s1 * 0.015625f;
        }
    }
    __syncthreads();

    {   // t1 partials over 8 waves
        constexpr int TI = (2*FS)/8;
        float a1 = 0.f;
        const float* Wp = Vw + (size_t)(wv*TI)*NSV + o;
        const float* mp = smL + wv*TI;
        #pragma unroll 8
        for (int k = 0; k < TI; ++k) a1 = fmaf(mp[k], Wp[(size_t)k*NSV], a1);
        red[wv*64 + ol] = a1;
    }
    __syncthreads();
    if (t < 64) {
        float s = Vb[o0 + t];
        #pragma unroll
        for (int g = 0; g < 8; ++g) s += red[g*64 + t];
        t1L[t] = s;
    }
    __syncthreads();

    {   // main GEMM: e_l = wv, full K
        float acc = t1L[ol];
        const float* Ap = As + wv*KP;                // wave-uniform base
        const float* Wp = Vw + (size_t)(2*FS)*NSV + o;
        #pragma unroll 8
        for (int k = 0; k < KP; ++k)
            acc = fmaf(Ap[k], Wp[(size_t)k*NSV], acc);
        red[wv*64 + ol] = tanhf(acc);
    }
    __syncthreads();
    if (t < 256) {
        const int e_l = t >> 5, c0 = (t & 31) * 2;
        gstore2(&svOut[(size_t)(e0+e_l)*NSV + o0 + c0],
                red[e_l*64 + c0], red[e_l*64 + c0 + 1]);
    }
    if (psumOut != nullptr && t < 32) {
        const int c0 = 2*t;
        float s0 = 0.f, s1 = 0.f;
        #pragma unroll
        for (int g = 0; g < 8; ++g) { s0 += red[g*64 + c0]; s1 += red[g*64 + c0 + 1]; }
        gstore2(&psumOut[(size_t)et*NSV + o0 + c0], s0, s1);
    }
}

// ---------------------------------------------------------------------------
// P5: heads + orbital matrices, per electron (128 blocks).
// ---------------------------------------------------------------------------
__device__ void headsw_role(int e, const float* __restrict__ svF,
                            const float* __restrict__ vhu_w, const float* __restrict__ vhu_b,
                            const float* __restrict__ vhd_w, const float* __restrict__ vhd_b,
                            const float* __restrict__ wu_w,  const float* __restrict__ wu_b,
                            const float* __restrict__ wd_w,  const float* __restrict__ wd_b,
                            const float* __restrict__ expv,  float* __restrict__ orb,
                            float* sh)
{
    float* row  = sh;          // 512
    float* redH = sh + 512;    // 512
    float* tmpL = sh + 1024;   // 256
    const int spin = e >> 6;
    const int t = threadIdx.x;
    if (t < 256) {
        float2 v = gload2(&svF[(size_t)e*NSV + 2*t]);
        row[2*t] = v.x; row[2*t+1] = v.y;
    }
    __syncthreads();

    const float* W1 = spin ? vhd_w : vhu_w;
    const float* B1 = spin ? vhd_b : vhu_b;
    {
        const int o = t & 255, kc = t >> 8;
        float acc = kc ? 0.f : B1[o];
        const float* Wp = W1 + (size_t)(kc*256)*256 + o;
        const float* rp = row + kc*256;
        #pragma unroll 8
        for (int f = 0; f < 256; ++f)
            acc = fmaf(rp[f], Wp[(size_t)f*256], acc);
        redH[t] = acc;
    }
    __syncthreads();
    if (t < 256) tmpL[t] = redH[t] + redH[256 + t];
    __syncthreads();

    const float* W2 = spin ? wd_w : wu_w;
    const float* B2 = spin ? wd_b : wu_b;
    {
        const int o = t & 63, kc = t >> 6;
        float acc = 0.f;
        const float* Wp = W2 + (size_t)(kc*32)*64 + o;
        const float* tp = tmpL + kc*32;
        #pragma unroll
        for (int f = 0; f < 32; ++f)
            acc = fmaf(tp[f], Wp[(size_t)f*64], acc);
        redH[kc*64 + o] = acc;
    }
    __syncthreads();
    if (t < 32) {
        const int c0 = 2*t;
        const float ex = gload(&expv[e]);
        float s0 = B2[c0], s1 = B2[c0+1];
        #pragma unroll
        for (int g = 0; g < 8; ++g) { s0 += redH[g*64 + c0]; s1 += redH[g*64 + c0 + 1]; }
        gstore2(&orb[(size_t)e*64 + c0], s0*ex, s1*ex);
    }
}

// ---------------------------------------------------------------------------
// Fused persistent kernel: 136 blocks x 512 threads, 6 phases, 5 barriers.
// ---------------------------------------------------------------------------
__global__ void __launch_bounds__(512)
fused_ansatz(const float* __restrict__ r,    const float* __restrict__ apos,
             const float* __restrict__ V0w,  const float* __restrict__ V0b,
             const float* __restrict__ W0w,  const float* __restrict__ W0b,
             const float* __restrict__ V1w,  const float* __restrict__ V1b,
             const float* __restrict__ W1w,  const float* __restrict__ W1b,
             const float* __restrict__ V2w,  const float* __restrict__ V2b,
             const float* __restrict__ W2w,  const float* __restrict__ W2b,
             const float* __restrict__ afw,  const float* __restrict__ afb,
             const float* __restrict__ vhuw, const float* __restrict__ vhub,
             const float* __restrict__ vhdw, const float* __restrict__ vhdb,
             const float* __restrict__ wuw,  const float* __restrict__ wub,
             const float* __restrict__ wdw,  const float* __restrict__ wdb,
             float* __restrict__ ws)
{
    __shared__ __align__(16) float sh[13984];
    const int b = blockIdx.x;
    const int t = threadIdx.x;

    float* sv0  = ws + OFF_SV0;
    float* svA  = ws + OFF_SVA;
    float* svB  = ws + OFF_SVB;
    float* expv = ws + OFF_EXPV;
    float* sm0g = ws + OFF_SM0;
    float* pme0 = ws + OFF_PME0;
    float* pme1 = ws + OFF_PME1;
    float* pme2 = ws + OFF_PME2;
    float* pme3 = ws + OFF_PME3;
    float* psA  = ws + OFF_PSA;
    float* psB  = ws + OFF_PSB;
    float* orb  = ws + OFF_ORB;

    // P0: pair chain (0..127) | smean0 from geometry (128..135)
    if (b < 128)
        pchain_role(b, r, apos, W0w, W0b, W1w, W1b, W2w, W2b,
                    sv0, expv, pme0, pme1, pme2, pme3, sh);
    else
        smean0_role(b - 128, r, apos, sm0g, sh);
    gsync(136);

    // P1..P4: s-stream GEMMs (blocks 0..127)
    if (b < 128) a2_role<128, 4, true  >(b, sv0, pme0, sm0g, V0w, V0b, svA, psA, sh);
    gsync(272);
    if (b < 128) a2_role<512, 64, false>(b, svA, pme1, psA, V1w, V1b, svB, psB, sh);
    gsync(408);
    if (b < 128) a2_role<512, 64, false>(b, svB, pme2, psB, V2w, V2b, svA, psA, sh);
    gsync(544);
    if (b < 128) a2_role<512, 64, false>(b, svA, pme3, psA, afw, afb, svB, nullptr, sh);
    gsync(680);

    // P5: heads + orbitals (blocks 0..127); det runs as its own dispatch
    if (b < 128)
        headsw_role(b, svB, vhuw, vhub, vhdw, vhdb, wuw, wub, wdw, wdb,
                    expv, orb, sh);

    // exit protocol: reset barrier state for the next graph replay
    __syncthreads();
    if (t == 0) {
        atomicAdd(&g_exit, 1u);
        if (b == 0) {
            while (__hip_atomic_load(&g_exit, __ATOMIC_RELAXED,
                                     __HIP_MEMORY_SCOPE_AGENT) < 136u)
                __builtin_amdgcn_s_sleep(2);
            atomicExch(&g_bar,  0u);
            atomicExch(&g_exit, 0u);
        }
    }
}

// ---------------------------------------------------------------------------
// det: two 64x64 log|det| LU, own dispatch (keeps rr[64] in registers — the
// R8 fused version spilled at VGPR=52). Cross-dispatch coherence is free.
// ---------------------------------------------------------------------------
__device__ __forceinline__ int imax2(int a, int b) { return a > b ? a : b; }
__device__ __forceinline__ float readlane_f(float x, int lane) {
    return __int_as_float(__builtin_amdgcn_readlane(__float_as_int(x), lane));
}

__global__ __launch_bounds__(128)
void det_kernel(const float* __restrict__ ws, float* __restrict__ out)
{
    const float* orb = ws + OFF_ORB;
    __shared__ float parts[2];
    const int t = threadIdx.x;
    const int w = t >> 6;
    const int lane = t & 63;
    const float* M = orb + (size_t)w*4096 + (size_t)lane*64;
    float rr[64];
    #pragma unroll
    for (int j = 0; j < 64; j += 4) {
        float4 v = *reinterpret_cast<const float4*>(M + j);
        rr[j]=v.x; rr[j+1]=v.y; rr[j+2]=v.z; rr[j+3]=v.w;
    }
    float pv_mine = 1.f;
    bool active = true;
    #pragma unroll
    for (int k = 0; k < 64; ++k) {
        int bits = (int)(__float_as_uint(rr[k]) & 0x7FFFFFC0u);
        int v = active ? (bits | lane) : lane;
        int tmp;
        tmp = __builtin_amdgcn_update_dpp(0, v, 0xB1,  0xF, 0xF, true); v = imax2(v, tmp);
        tmp = __builtin_amdgcn_update_dpp(0, v, 0x4E,  0xF, 0xF, true); v = imax2(v, tmp);
        tmp = __builtin_amdgcn_update_dpp(0, v, 0x141, 0xF, 0xF, true); v = imax2(v, tmp);
        tmp = __builtin_amdgcn_update_dpp(0, v, 0x140, 0xF, 0xF, true); v = imax2(v, tmp);
        tmp = __builtin_amdgcn_update_dpp(0, v, 0x142, 0xF, 0xF, true); v = imax2(v, tmp);
        tmp = __builtin_amdgcn_update_dpp(0, v, 0x143, 0xF, 0xF, true); v = imax2(v, tmp);
        const int idx = __builtin_amdgcn_readlane(v, 63) & 63;
        const float piv = readlane_f(rr[k], idx);
        pv_mine = (lane == k) ? piv : pv_mine;
        const float linv = __builtin_amdgcn_rcpf(piv);
        const float l = (active && lane != idx) ? rr[k]*linv : 0.f;
        if (lane == idx) active = false;
        #pragma unroll
        for (int j = k+1; j < 64; ++j)
            rr[j] = fmaf(-l, readlane_f(rr[j], idx), rr[j]);
    }
    float lg = logf(fabsf(pv_mine));
    #pragma unroll
    for (int off = 32; off; off >>= 1) lg += __shfl_down(lg, off);
    if (lane == 0) parts[w] = lg;
    __syncthreads();
    if (t == 0) out[0] = parts[0] + parts[1];
}

// ---------------------------------------------------------------------------
extern "C" void kernel_launch(void* const* d_in, const int* in_sizes, int n_in,
                              void* d_out, int out_size, void* d_ws, size_t ws_size,
                              hipStream_t stream)
{
    const float* r    = (const float*)d_in[0];
    const float* apos = (const float*)d_in[1];
    const float* V0w  = (const float*)d_in[2];
    const float* V0b  = (const float*)d_in[3];
    const float* W0w  = (const float*)d_in[4];
    const float* W0b  = (const float*)d_in[5];
    const float* V1w  = (const float*)d_in[6];
    const float* V1b  = (const float*)d_in[7];
    const float* W1w  = (const float*)d_in[8];
    const float* W1b  = (const float*)d_in[9];
    const float* V2w  = (const float*)d_in[10];
    const float* V2b  = (const float*)d_in[11];
    const float* W2w  = (const float*)d_in[12];
    const float* W2b  = (const float*)d_in[13];
    const float* afw  = (const float*)d_in[14];
    const float* afb  = (const float*)d_in[15];
    const float* vhuw = (const float*)d_in[16];
    const float* vhub = (const float*)d_in[17];
    const float* vhdw = (const float*)d_in[18];
    const float* vhdb = (const float*)d_in[19];
    const float* wuw  = (const float*)d_in[20];
    const float* wub  = (const float*)d_in[21];
    const float* wdw  = (const float*)d_in[22];
    const float* wdb  = (const float*)d_in[23];

    fused_ansatz<<<dim3(136), dim3(512), 0, stream>>>(
        r, apos, V0w, V0b, W0w, W0b, V1w, V1b, W1w, W1b,
        V2w, V2b, W2w, W2b, afw, afb, vhuw, vhub, vhdw, vhdb,
        wuw, wub, wdw, wdb, (float*)d_ws);
    det_kernel<<<1, 128, 0, stream>>>((const float*)d_ws, (float*)d_out);
}

// Round 10
// 132.682 us; speedup vs baseline: 1.0450x; 1.0450x over previous
//
#include <hip/hip_runtime.h>
#include <math.h>

#define NSV 512

// ---------------------------------------------------------------------------
// K1: front — pair-stream chain + layer-0 s-GEMM, one block per electron j.
// pchain runs entirely in LDS (p never hits memory); sv0[j], pme0[j] stay
// block-local; smean0 + t1_0 are recomputed per block from raw geometry
// (cheap, removes the A0 dispatch + all sv0/pme0 global traffic).
// Outputs: svA row j, expv[j], pme1/2/3 row j.
// ---------------------------------------------------------------------------
__global__ __launch_bounds__(512)
void front_kernel(const float* __restrict__ r,   const float* __restrict__ apos,
                  const float* __restrict__ V0w, const float* __restrict__ V0b,
                  const float* __restrict__ W0w, const float* __restrict__ W0b,
                  const float* __restrict__ W1w, const float* __restrict__ W1b,
                  const float* __restrict__ W2w, const float* __restrict__ W2b,
                  float* __restrict__ svA,  float* __restrict__ expv,
                  float* __restrict__ pme1, float* __restrict__ pme2,
                  float* __restrict__ pme3)
{
    __shared__ __align__(16) float sh[14984];
    float* rL    = sh;            // 384
    float* W0l   = sh + 384;      // 256
    float* svj   = sh + 640;      // 128
    float* shex  = sh + 768;      // 32
    float* pme0j = sh + 800;      // 8
    float* aposL = sh + 808;      // 96
    float* sm0   = sh + 904;      // 256
    float* p0c   = sh + 1160;     // 512
    float* PA    = sh + 1672;     // 128*68 = 8704
    float* Wbuf  = sh + 10376;    // 4096
    float* t1L   = sh + 14472;    // 512 (also sm0 scratch)

    const int j = blockIdx.x;
    const int t = threadIdx.x;
    const int i  = t >> 2;
    const int o0 = (t & 3) * 16;

    if (t < 384) rL[t] = r[t];
    if (t < 96)  aposL[t] = apos[t];
    for (int idx = t; idx < 4096; idx += 512) Wbuf[idx] = W1w[idx];
    if (t < 256) W0l[t] = W0w[t];
    __syncthreads();

    const float rjx = rL[j*3+0], rjy = rL[j*3+1], rjz = rL[j*3+2];
    if (t < 128) {     // p0 column j: p0[i][j] = r[j]-r[i], len (0 on diag)
        const int ii = t;
        float dx = rjx - rL[ii*3+0], dy = rjy - rL[ii*3+1], dz = rjz - rL[ii*3+2];
        float len = (ii == j) ? 0.f : sqrtf(dx*dx + dy*dy + dz*dz);
        p0c[ii*4+0]=dx; p0c[ii*4+1]=dy; p0c[ii*4+2]=dz; p0c[ii*4+3]=len;
    } else if (t < 160) {   // sv0 row j (LDS only) + exp terms
        const int k = t - 128;
        float dx = rjx - aposL[k*3+0], dy = rjy - aposL[k*3+1], dz = rjz - aposL[k*3+2];
        float len = sqrtf(dx*dx + dy*dy + dz*dz);
        svj[k*4+0]=dx; svj[k*4+1]=dy; svj[k*4+2]=dz; svj[k*4+3]=len;
        shex[k] = expf(-len);
    }
    __syncthreads();

    {   // layer0: PA[i][o] = tanh(p0c[i] @ W0 + b0)
        const float x0=p0c[i*4+0], x1=p0c[i*4+1], x2=p0c[i*4+2], x3=p0c[i*4+3];
        #pragma unroll
        for (int k = 0; k < 16; ++k) {
            const int o = o0 + k;
            float acc = W0b[o];
            acc = fmaf(x0, W0l[o],     acc);
            acc = fmaf(x1, W0l[64+o],  acc);
            acc = fmaf(x2, W0l[128+o], acc);
            acc = fmaf(x3, W0l[192+o], acc);
            PA[i*68+o] = tanhf(acc);
        }
    }
    if (t < 8) {        // pme0[j] — LDS only
        const int spin = t >> 2, c = t & 3;
        float s = 0.f;
        #pragma unroll 8
        for (int k = 0; k < 64; ++k) s += p0c[(spin*64+k)*4 + c];
        pme0j[t] = s * 0.015625f;
    }
    if (t == 8) {
        float s = 0.f;
        #pragma unroll 8
        for (int k = 0; k < 32; ++k) s += shex[k];
        expv[j] = s;
    }
    __syncthreads();

    // pme1 (global) + layer1 compute
    if (t < 128) {
        const int spin = t >> 6, c = t & 63;
        float s = 0.f;
        #pragma unroll 8
        for (int k = 0; k < 64; ++k) s += PA[(spin*64+k)*68 + c];
        pme1[j*128 + t] = s * 0.015625f;
    }
    float acc[16], res[16];
    const float* pa = PA + i*68;
    {
        #pragma unroll
        for (int k = 0; k < 16; ++k) acc[k] = W1b[o0+k];
        #pragma unroll 4
        for (int c = 0; c < 64; ++c) {
            const float av = pa[c];
            const float* wr = Wbuf + c*64 + o0;
            float4 wa = *reinterpret_cast<const float4*>(wr);
            float4 wb = *reinterpret_cast<const float4*>(wr+4);
            float4 wc = *reinterpret_cast<const float4*>(wr+8);
            float4 wd = *reinterpret_cast<const float4*>(wr+12);
            acc[0] =fmaf(av,wa.x,acc[0]);  acc[1] =fmaf(av,wa.y,acc[1]);
            acc[2] =fmaf(av,wa.z,acc[2]);  acc[3] =fmaf(av,wa.w,acc[3]);
            acc[4] =fmaf(av,wb.x,acc[4]);  acc[5] =fmaf(av,wb.y,acc[5]);
            acc[6] =fmaf(av,wb.z,acc[6]);  acc[7] =fmaf(av,wb.w,acc[7]);
            acc[8] =fmaf(av,wc.x,acc[8]);  acc[9] =fmaf(av,wc.y,acc[9]);
            acc[10]=fmaf(av,wc.z,acc[10]); acc[11]=fmaf(av,wc.w,acc[11]);
            acc[12]=fmaf(av,wd.x,acc[12]); acc[13]=fmaf(av,wd.y,acc[13]);
            acc[14]=fmaf(av,wd.z,acc[14]); acc[15]=fmaf(av,wd.w,acc[15]);
        }
        #pragma unroll
        for (int k = 0; k < 16; ++k) res[k] = pa[o0+k];
    }
    __syncthreads();
    #pragma unroll
    for (int k = 0; k < 16; ++k) PA[i*68+o0+k] = tanhf(acc[k]) + res[k];
    __syncthreads();

    // pme2 (global) + restage W2
    if (t < 128) {
        const int spin = t >> 6, c = t & 63;
        float s = 0.f;
        #pragma unroll 8
        for (int k = 0; k < 64; ++k) s += PA[(spin*64+k)*68 + c];
        pme2[j*128 + t] = s * 0.015625f;
    }
    for (int idx = t; idx < 4096; idx += 512) Wbuf[idx] = W2w[idx];
    __syncthreads();

    {   // layer2 compute
        #pragma unroll
        for (int k = 0; k < 16; ++k) acc[k] = W2b[o0+k];
        #pragma unroll 4
        for (int c = 0; c < 64; ++c) {
            const float av = pa[c];
            const float* wr = Wbuf + c*64 + o0;
            float4 wa = *reinterpret_cast<const float4*>(wr);
            float4 wb = *reinterpret_cast<const float4*>(wr+4);
            float4 wc = *reinterpret_cast<const float4*>(wr+8);
            float4 wd = *reinterpret_cast<const float4*>(wr+12);
            acc[0] =fmaf(av,wa.x,acc[0]);  acc[1] =fmaf(av,wa.y,acc[1]);
            acc[2] =fmaf(av,wa.z,acc[2]);  acc[3] =fmaf(av,wa.w,acc[3]);
            acc[4] =fmaf(av,wb.x,acc[4]);  acc[5] =fmaf(av,wb.y,acc[5]);
            acc[6] =fmaf(av,wb.z,acc[6]);  acc[7] =fmaf(av,wb.w,acc[7]);
            acc[8] =fmaf(av,wc.x,acc[8]);  acc[9] =fmaf(av,wc.y,acc[9]);
            acc[10]=fmaf(av,wc.z,acc[10]); acc[11]=fmaf(av,wc.w,acc[11]);
            acc[12]=fmaf(av,wd.x,acc[12]); acc[13]=fmaf(av,wd.y,acc[13]);
            acc[14]=fmaf(av,wd.z,acc[14]); acc[15]=fmaf(av,wd.w,acc[15]);
        }
        #pragma unroll
        for (int k = 0; k < 16; ++k) res[k] = pa[o0+k];
    }
    __syncthreads();
    #pragma unroll
    for (int k = 0; k < 16; ++k) PA[i*68+o0+k] = tanhf(acc[k]) + res[k];
    __syncthreads();

    if (t < 128) {   // pme3 (global)
        const int spin = t >> 6, c = t & 63;
        float s = 0.f;
        #pragma unroll 8
        for (int k = 0; k < 64; ++k) s += PA[(spin*64+k)*68 + c];
        pme3[j*128 + t] = s * 0.015625f;
    }

    // ---- smean0 from geometry (redundant per block; 2 half-sums/thread) ----
    {
        const int out = t >> 1, half = t & 1;
        const int spin = out >> 7, cc = out & 127, a_i = cc >> 2, d = cc & 3;
        const float ax = aposL[a_i*3+0], ay = aposL[a_i*3+1], az = aposL[a_i*3+2];
        float s = 0.f;
        #pragma unroll 8
        for (int q = 0; q < 32; ++q) {
            const int e = spin*64 + half*32 + q;
            float dx = rL[e*3+0]-ax, dy = rL[e*3+1]-ay, dz = rL[e*3+2]-az;
            float len = sqrtf(dx*dx + dy*dy + dz*dz);
            s += (d==0)?dx:(d==1)?dy:(d==2)?dz:len;
        }
        t1L[t] = s;    // scratch
    }
    __syncthreads();
    if (t < 256) sm0[t] = (t1L[2*t] + t1L[2*t+1]) * 0.015625f;
    __syncthreads();

    // ---- t1_0 then A0 for electron j (thread t = output o) ----
    {
        const int o = t;
        float a0 = V0b[o];
        #pragma unroll 8
        for (int c = 0; c < 256; ++c)
            a0 = fmaf(sm0[c], V0w[(size_t)c*NSV + o], a0);
        #pragma unroll
        for (int c = 0; c < 8; ++c)
            a0 = fmaf(pme0j[c], V0w[(size_t)(256+c)*NSV + o], a0);
        #pragma unroll 8
        for (int f = 0; f < 128; ++f)
            a0 = fmaf(svj[f], V0w[(size_t)(264+f)*NSV + o], a0);
        svA[(size_t)j*NSV + o] = tanhf(a0);
    }
}

// ---------------------------------------------------------------------------
// A kernel (R7-proven): s-stream GEMM. 256 blocks x 512 threads, tile 4e x 64o.
// COLSUM=true: smean from svIn column sums (64-deep); else from psum tiles.
// Emits psumOut[et][o] per-block column sums for the next layer's smean.
// ---------------------------------------------------------------------------
template<int FS, int FP, bool COLSUM>
__global__ __launch_bounds__(512)
void a2_kernel(const float* __restrict__ svIn, const float* __restrict__ pmeIn,
               const float* __restrict__ psumIn,
               const float* __restrict__ Vw, const float* __restrict__ Vb,
               float* __restrict__ svOut, float* __restrict__ psumOut)
{
    constexpr int KP  = 2*FP + FS;        // 640
    constexpr int KP2 = KP/2;
    __shared__ __align__(16) float As[4*KP];
    __shared__ __align__(16) float smL[2*FS];
    __shared__ __align__(16) float red[512];
    __shared__ float t1L[64];
    const int t  = threadIdx.x;
    const int et = blockIdx.x >> 3;
    const int e0 = et * 4;
    const int o0 = (blockIdx.x & 7) * 64;
    const int ol = t & 63;
    const int o  = o0 + ol;
    const int wv = t >> 6;                // 0..7

    for (int idx = t; idx < 4*2*FP; idx += 512)
        As[(idx/(2*FP))*KP + idx%(2*FP)] =
            pmeIn[(size_t)(e0 + idx/(2*FP))*(2*FP) + idx%(2*FP)];
    for (int idx = t; idx < FS; idx += 512) {     // 4 rows x FS/4 float4s
        const int row = idx / (FS/4), c4 = idx % (FS/4);
        *reinterpret_cast<float4*>(&As[row*KP + 2*FP + c4*4]) =
            *reinterpret_cast<const float4*>(&svIn[(size_t)(e0+row)*FS + c4*4]);
    }
    if (COLSUM) {
        for (int idx = t; idx < 2*FS; idx += 512) {
            const int col = (idx < FS) ? idx : idx - FS;
            const int i0  = (idx < FS) ? 0 : 64;
            const float* base = svIn + (size_t)i0*FS + col;
            float s = 0.f;
            #pragma unroll 8
            for (int k = 0; k < 64; ++k) s += base[(size_t)k*FS];
            smL[idx] = s * 0.015625f;
        }
    } else {
        for (int idx = t; idx < 2*FS; idx += 512) {
            const int col = (idx < FS) ? idx : idx - FS;
            const int r0  = (idx < FS) ? 0 : 16;
            const float* base = psumIn + (size_t)r0*NSV + col;
            float s = 0.f;
            #pragma unroll
            for (int k = 0; k < 16; ++k) s += base[(size_t)k*NSV];
            smL[idx] = s * 0.015625f;
        }
    }
    __syncthreads();

    {   // t1 partials over 8 waves: t1[o] = Vb[o] + smean . Vw[0:2FS]
        constexpr int TI = (2*FS)/8;
        float a1 = 0.f;
        const float* Wp = Vw + (size_t)(wv*TI)*NSV + o;
        const float* mp = smL + wv*TI;
        #pragma unroll 8
        for (int k = 0; k < TI; ++k) a1 = fmaf(mp[k], Wp[(size_t)k*NSV], a1);
        red[wv*64 + ol] = a1;
    }
    __syncthreads();
    if (t < 64) {
        float s = Vb[o0 + t];
        #pragma unroll
        for (int g = 0; g < 8; ++g) s += red[g*64 + t];
        t1L[t] = s;
    }
    __syncthreads();

    const int e_l = wv & 3, kh = wv >> 2;
    {   // main GEMM, K split in halves across wave groups
        float a2 = (kh == 0) ? t1L[ol] : 0.f;
        const float* Ap = As + e_l*KP + kh*KP2;          // wave-uniform base
        const float* Wp = Vw + (size_t)(2*FS + kh*KP2)*NSV + o;
        #pragma unroll 16
        for (int k = 0; k < KP2; ++k)
            a2 = fmaf(Ap[k], Wp[(size_t)k*NSV], a2);
        red[wv*64 + ol] = a2;
    }
    __syncthreads();
    float v = 0.f;
    if (t < 256) {
        v = tanhf(red[(t>>6)*64 + (t&63)] + red[((t>>6)+4)*64 + (t&63)]);
        svOut[(size_t)(e0 + (t>>6))*NSV + o0 + (t&63)] = v;
    }
    if (psumOut) {
        __syncthreads();
        if (t < 256) red[t] = v;
        __syncthreads();
        if (t < 64) {
            float s = red[t] + red[64+t] + red[128+t] + red[192+t];
            psumOut[(size_t)et*NSV + o0 + t] = s;        // unscaled col sums
        }
    }
}

// ---------------------------------------------------------------------------
// heads + orbital matrices, per electron. 128 blocks x 512 threads.
// ---------------------------------------------------------------------------
__global__ __launch_bounds__(512)
void headsw_kernel(const float* __restrict__ svF,
                   const float* __restrict__ vhu_w, const float* __restrict__ vhu_b,
                   const float* __restrict__ vhd_w, const float* __restrict__ vhd_b,
                   const float* __restrict__ wu_w,  const float* __restrict__ wu_b,
                   const float* __restrict__ wd_w,  const float* __restrict__ wd_b,
                   const float* __restrict__ expv,  float* __restrict__ orb)
{
    __shared__ __align__(16) float row[512];
    __shared__ __align__(16) float redH[512];
    __shared__ __align__(16) float tmpL[256];
    const int e = blockIdx.x;
    const int spin = e >> 6;
    const int t = threadIdx.x;
    row[t] = svF[(size_t)e*NSV + t];
    __syncthreads();

    const float* W1 = spin ? vhd_w : vhu_w;
    const float* B1 = spin ? vhd_b : vhu_b;
    {
        const int o = t & 255, kc = t >> 8;       // kc in {0,1}
        float acc = kc ? 0.f : B1[o];
        const float* Wp = W1 + (size_t)(kc*256)*256 + o;
        const float* rp = row + kc*256;
        #pragma unroll 8
        for (int f = 0; f < 256; ++f)
            acc = fmaf(rp[f], Wp[(size_t)f*256], acc);
        redH[t] = acc;
    }
    __syncthreads();
    if (t < 256) tmpL[t] = redH[t] + redH[256 + t];
    __syncthreads();

    const float* W2 = spin ? wd_w : wu_w;
    const float* B2 = spin ? wd_b : wu_b;
    {
        const int o = t & 63, kc = t >> 6;        // kc in 0..7
        float acc = 0.f;
        const float* Wp = W2 + (size_t)(kc*32)*64 + o;
        const float* tp = tmpL + kc*32;
        #pragma unroll
        for (int f = 0; f < 32; ++f)
            acc = fmaf(tp[f], Wp[(size_t)f*64], acc);
        redH[kc*64 + o] = acc;
    }
    __syncthreads();
    if (t < 64) {
        float s = B2[t];
        #pragma unroll
        for (int g = 0; g < 8; ++g) s += redH[g*64 + t];
        orb[(size_t)e*64 + t] = s * expv[e];
    }
}

// ---------------------------------------------------------------------------
// det: two 64x64 log|det| via partial-pivot LU, one wave per matrix.
// DPP packed argmax, bit-cast v_readlane broadcasts, deferred log.
// ---------------------------------------------------------------------------
__device__ __forceinline__ int imax2(int a, int b) { return a > b ? a : b; }
__device__ __forceinline__ float readlane_f(float x, int lane) {
    return __int_as_float(__builtin_amdgcn_readlane(__float_as_int(x), lane));
}

__global__ __launch_bounds__(128)
void det_kernel(const float* __restrict__ orb, float* __restrict__ out)
{
    __shared__ float parts[2];
    const int t = threadIdx.x;
    const int w = t >> 6;
    const int lane = t & 63;
    const float* M = orb + (size_t)w*4096 + (size_t)lane*64;
    float rr[64];
    #pragma unroll
    for (int j = 0; j < 64; j += 4) {
        float4 v = *reinterpret_cast<const float4*>(M + j);
        rr[j]=v.x; rr[j+1]=v.y; rr[j+2]=v.z; rr[j+3]=v.w;
    }
    float pv_mine = 1.f;
    bool active = true;
    #pragma unroll
    for (int k = 0; k < 64; ++k) {
        int bits = (int)(__float_as_uint(rr[k]) & 0x7FFFFFC0u);
        int v = active ? (bits | lane) : lane;
        int tmp;
        tmp = __builtin_amdgcn_update_dpp(0, v, 0xB1,  0xF, 0xF, true); v = imax2(v, tmp);
        tmp = __builtin_amdgcn_update_dpp(0, v, 0x4E,  0xF, 0xF, true); v = imax2(v, tmp);
        tmp = __builtin_amdgcn_update_dpp(0, v, 0x141, 0xF, 0xF, true); v = imax2(v, tmp);
        tmp = __builtin_amdgcn_update_dpp(0, v, 0x140, 0xF, 0xF, true); v = imax2(v, tmp);
        tmp = __builtin_amdgcn_update_dpp(0, v, 0x142, 0xF, 0xF, true); v = imax2(v, tmp);
        tmp = __builtin_amdgcn_update_dpp(0, v, 0x143, 0xF, 0xF, true); v = imax2(v, tmp);
        const int idx = __builtin_amdgcn_readlane(v, 63) & 63;
        const float piv = readlane_f(rr[k], idx);
        pv_mine = (lane == k) ? piv : pv_mine;
        const float linv = __builtin_amdgcn_rcpf(piv);
        const float l = (active && lane != idx) ? rr[k]*linv : 0.f;
        if (lane == idx) active = false;
        #pragma unroll
        for (int j = k+1; j < 64; ++j)
            rr[j] = fmaf(-l, readlane_f(rr[j], idx), rr[j]);
    }
    float lg = logf(fabsf(pv_mine));
    #pragma unroll
    for (int off = 32; off; off >>= 1) lg += __shfl_down(lg, off);
    if (lane == 0) parts[w] = lg;
    __syncthreads();
    if (t == 0) out[0] = parts[0] + parts[1];
}

// ---------------------------------------------------------------------------
extern "C" void kernel_launch(void* const* d_in, const int* in_sizes, int n_in,
                              void* d_out, int out_size, void* d_ws, size_t ws_size,
                              hipStream_t stream)
{
    const float* r    = (const float*)d_in[0];
    const float* apos = (const float*)d_in[1];
    const float* V0w  = (const float*)d_in[2];
    const float* V0b  = (const float*)d_in[3];
    const float* W0w  = (const float*)d_in[4];
    const float* W0b  = (const float*)d_in[5];
    const float* V1w  = (const float*)d_in[6];
    const float* V1b  = (const float*)d_in[7];
    const float* W1w  = (const float*)d_in[8];
    const float* W1b  = (const float*)d_in[9];
    const float* V2w  = (const float*)d_in[10];
    const float* V2b  = (const float*)d_in[11];
    const float* W2w  = (const float*)d_in[12];
    const float* W2b  = (const float*)d_in[13];
    const float* afw  = (const float*)d_in[14];
    const float* afb  = (const float*)d_in[15];
    const float* vhuw = (const float*)d_in[16];
    const float* vhub = (const float*)d_in[17];
    const float* vhdw = (const float*)d_in[18];
    const float* vhdb = (const float*)d_in[19];
    const float* wuw  = (const float*)d_in[20];
    const float* wub  = (const float*)d_in[21];
    const float* wdw  = (const float*)d_in[22];
    const float* wdb  = (const float*)d_in[23];

    float* ws   = (float*)d_ws;
    float* svA  = ws;              // 65536
    float* svB  = svA  + 65536;    // 65536
    float* expv = svB  + 65536;    // 128
    float* pme1 = expv + 128;      // 16384
    float* pme2 = pme1 + 16384;    // 16384
    float* pme3 = pme2 + 16384;    // 16384
    float* psA  = pme3 + 16384;    // 16384
    float* psB  = psA  + 16384;    // 16384
    float* orb  = psB  + 16384;    // 8192

    // K1: pchain + A0 fused (sv0/pme0 never hit global)
    front_kernel<<<128, 512, 0, stream>>>(r, apos, V0w, V0b, W0w, W0b,
                                          W1w, W1b, W2w, W2b,
                                          svA, expv, pme1, pme2, pme3);
    // K2: A1 — smean via direct column sums of svA
    a2_kernel<512, 64, true ><<<256, 512, 0, stream>>>(svA, pme1, nullptr, V1w, V1b, svB, psB);
    // K3: A2 — smean via psB
    a2_kernel<512, 64, false><<<256, 512, 0, stream>>>(svB, pme2, psB, V2w, V2b, svA, psA);
    // K4: A3 (after-layer) — smean via psA
    a2_kernel<512, 64, false><<<256, 512, 0, stream>>>(svA, pme3, psA, afw, afb, svB, nullptr);
    // K5: heads + orbitals
    headsw_kernel<<<128, 512, 0, stream>>>(svB, vhuw, vhub, vhdw, vhdb,
                                           wuw, wub, wdw, wdb, expv, orb);
    // K6: determinants
    det_kernel<<<1, 128, 0, stream>>>(orb, (float*)d_out);
}

// Round 11
// 105.450 us; speedup vs baseline: 1.3148x; 1.2582x over previous
//
#include <hip/hip_runtime.h>
#include <math.h>

#define NSV 512

// ---------------------------------------------------------------------------
// K1: pchain split by spin-half. Grid 256: block b -> (j = b>>1, sp = b&1)
// owns rows i in [sp*64, sp*64+64) of pair-column j, entirely in LDS.
// Emits pme0/1/2/3 spin-halves (block-local sums), sv0 row j + expv[j] (sp=0).
// The p tensor never touches global memory.
// ---------------------------------------------------------------------------
__global__ __launch_bounds__(512)
void pchain_kernel(const float* __restrict__ r, const float* __restrict__ apos,
                   const float* __restrict__ W0w, const float* __restrict__ W0b,
                   const float* __restrict__ W1w, const float* __restrict__ W1b,
                   const float* __restrict__ W2w, const float* __restrict__ W2b,
                   float* __restrict__ sv0, float* __restrict__ expv,
                   float* __restrict__ pme0, float* __restrict__ pme1,
                   float* __restrict__ pme2, float* __restrict__ pme3)
{
    __shared__ __align__(16) float sh[9472];
    float* rL    = sh;           // 384
    float* W0l   = sh + 384;     // 256
    float* aposL = sh + 640;     // 96
    float* shex  = sh + 736;     // 32
    float* p0c   = sh + 768;     // 64*4
    float* PA    = sh + 1024;    // 64*68 = 4352
    float* Wbuf  = sh + 5376;    // 4096
    const int b  = blockIdx.x;
    const int j  = b >> 1, sp = b & 1;
    const int t  = threadIdx.x;
    const int i  = t >> 3;          // local row 0..63
    const int o0 = (t & 7) * 8;     // 8 outputs per thread

    if (t < 384) rL[t] = r[t];
    else if (t < 480) aposL[t - 384] = apos[t - 384];
    for (int idx = t; idx < 4096; idx += 512) Wbuf[idx] = W1w[idx];
    if (t < 256) W0l[t] = W0w[t];
    __syncthreads();

    const float rjx = rL[j*3+0], rjy = rL[j*3+1], rjz = rL[j*3+2];
    if (t < 64) {        // p0 rows sp*64+t of column j
        const int ii = sp*64 + t;
        float dx = rjx - rL[ii*3+0], dy = rjy - rL[ii*3+1], dz = rjz - rL[ii*3+2];
        float len = (ii == j) ? 0.f : sqrtf(dx*dx + dy*dy + dz*dz);
        p0c[t*4+0]=dx; p0c[t*4+1]=dy; p0c[t*4+2]=dz; p0c[t*4+3]=len;
    } else if (sp == 0 && t < 96) {   // sv0 row j + exp terms
        const int k = t - 64;
        float dx = rjx - aposL[k*3+0], dy = rjy - aposL[k*3+1], dz = rjz - aposL[k*3+2];
        float len = sqrtf(dx*dx + dy*dy + dz*dz);
        float* spp = sv0 + (size_t)j*128 + k*4;
        spp[0]=dx; spp[1]=dy; spp[2]=dz; spp[3]=len;
        shex[k] = expf(-len);
    }
    __syncthreads();

    {   // layer0: PA[i][o] = tanh(p0c[i] @ W0 + b0), 8 outputs/thread
        const float x0=p0c[i*4+0], x1=p0c[i*4+1], x2=p0c[i*4+2], x3=p0c[i*4+3];
        #pragma unroll
        for (int k = 0; k < 8; ++k) {
            const int o = o0 + k;
            float a = W0b[o];
            a = fmaf(x0, W0l[o],     a);
            a = fmaf(x1, W0l[64+o],  a);
            a = fmaf(x2, W0l[128+o], a);
            a = fmaf(x3, W0l[192+o], a);
            PA[i*68+o] = tanhf(a);
        }
    }
    if (t < 4) {         // pme0 spin-half (4 features)
        float s = 0.f;
        #pragma unroll 8
        for (int k = 0; k < 64; ++k) s += p0c[k*4 + t];
        pme0[j*8 + sp*4 + t] = s * 0.015625f;
    }
    if (sp == 0 && t == 4) {
        float s = 0.f;
        #pragma unroll 8
        for (int k = 0; k < 32; ++k) s += shex[k];
        expv[j] = s;
    }
    __syncthreads();

    // pme1 spin-half + layer1 (W1, +res)
    if (t < 64) {
        float s = 0.f;
        #pragma unroll 8
        for (int k = 0; k < 64; ++k) s += PA[k*68 + t];
        pme1[j*128 + sp*64 + t] = s * 0.015625f;
    }
    float acc[8], res[8];
    const float* pa = PA + i*68;
    {
        #pragma unroll
        for (int k = 0; k < 8; ++k) acc[k] = W1b[o0+k];
        #pragma unroll 4
        for (int c = 0; c < 64; ++c) {
            const float av = pa[c];
            const float* wr = Wbuf + c*64 + o0;
            float4 wa = *reinterpret_cast<const float4*>(wr);
            float4 wb = *reinterpret_cast<const float4*>(wr+4);
            acc[0]=fmaf(av,wa.x,acc[0]); acc[1]=fmaf(av,wa.y,acc[1]);
            acc[2]=fmaf(av,wa.z,acc[2]); acc[3]=fmaf(av,wa.w,acc[3]);
            acc[4]=fmaf(av,wb.x,acc[4]); acc[5]=fmaf(av,wb.y,acc[5]);
            acc[6]=fmaf(av,wb.z,acc[6]); acc[7]=fmaf(av,wb.w,acc[7]);
        }
        #pragma unroll
        for (int k = 0; k < 8; ++k) res[k] = pa[o0+k];
    }
    __syncthreads();
    #pragma unroll
    for (int k = 0; k < 8; ++k) PA[i*68+o0+k] = tanhf(acc[k]) + res[k];
    __syncthreads();

    // pme2 spin-half + restage Wbuf = W2
    if (t < 64) {
        float s = 0.f;
        #pragma unroll 8
        for (int k = 0; k < 64; ++k) s += PA[k*68 + t];
        pme2[j*128 + sp*64 + t] = s * 0.015625f;
    }
    for (int idx = t; idx < 4096; idx += 512) Wbuf[idx] = W2w[idx];
    __syncthreads();

    {   // layer2 (W2, +res)
        #pragma unroll
        for (int k = 0; k < 8; ++k) acc[k] = W2b[o0+k];
        #pragma unroll 4
        for (int c = 0; c < 64; ++c) {
            const float av = pa[c];
            const float* wr = Wbuf + c*64 + o0;
            float4 wa = *reinterpret_cast<const float4*>(wr);
            float4 wb = *reinterpret_cast<const float4*>(wr+4);
            acc[0]=fmaf(av,wa.x,acc[0]); acc[1]=fmaf(av,wa.y,acc[1]);
            acc[2]=fmaf(av,wa.z,acc[2]); acc[3]=fmaf(av,wa.w,acc[3]);
            acc[4]=fmaf(av,wb.x,acc[4]); acc[5]=fmaf(av,wb.y,acc[5]);
            acc[6]=fmaf(av,wb.z,acc[6]); acc[7]=fmaf(av,wb.w,acc[7]);
        }
        #pragma unroll
        for (int k = 0; k < 8; ++k) res[k] = pa[o0+k];
    }
    __syncthreads();
    #pragma unroll
    for (int k = 0; k < 8; ++k) PA[i*68+o0+k] = tanhf(acc[k]) + res[k];
    __syncthreads();

    if (t < 64) {        // pme3 spin-half
        float s = 0.f;
        #pragma unroll 8
        for (int k = 0; k < 64; ++k) s += PA[k*68 + t];
        pme3[j*128 + sp*64 + t] = s * 0.015625f;
    }
}

// ---------------------------------------------------------------------------
// A kernel: s-stream GEMM. 256 blocks x 512 threads, tile 4e x 64o.
// GEOM=true (layer 0): smean recomputed from raw geometry (cheap, avoids the
// strided sv0 column sums). GEOM=false: smean from psum tiles (16 rows/spin).
// Emits psumOut[et][o] per-block column sums for the next layer's smean.
// ---------------------------------------------------------------------------
template<int FS, int FP, bool GEOM>
__global__ __launch_bounds__(512)
void a2_kernel(const float* __restrict__ svIn, const float* __restrict__ pmeIn,
               const float* __restrict__ psumIn,
               const float* __restrict__ r, const float* __restrict__ apos,
               const float* __restrict__ Vw, const float* __restrict__ Vb,
               float* __restrict__ svOut, float* __restrict__ psumOut)
{
    constexpr int KP  = 2*FP + FS;        // 136 (L0) or 640
    constexpr int KP2 = KP/2;
    __shared__ __align__(16) float As[4*KP];
    __shared__ __align__(16) float smL[2*FS];
    __shared__ __align__(16) float red[512];
    __shared__ float t1L[64];
    __shared__ float rL[384];
    __shared__ float aposL[96];
    const int t  = threadIdx.x;
    const int et = blockIdx.x >> 3;
    const int e0 = et * 4;
    const int o0 = (blockIdx.x & 7) * 64;
    const int ol = t & 63;
    const int o  = o0 + ol;
    const int wv = t >> 6;                // 0..7

    for (int idx = t; idx < 4*2*FP; idx += 512)
        As[(idx/(2*FP))*KP + idx%(2*FP)] =
            pmeIn[(size_t)(e0 + idx/(2*FP))*(2*FP) + idx%(2*FP)];
    for (int idx = t; idx < FS; idx += 512) {     // 4 rows x FS/4 float4s
        const int row = idx / (FS/4), c4 = idx % (FS/4);
        *reinterpret_cast<float4*>(&As[row*KP + 2*FP + c4*4]) =
            *reinterpret_cast<const float4*>(&svIn[(size_t)(e0+row)*FS + c4*4]);
    }
    if (GEOM) {
        if (t < 384) rL[t] = r[t];
        else if (t < 480) aposL[t - 384] = apos[t - 384];
        __syncthreads();
        {   // half-sums: out = spin*128 + a_i*4 + d, 32 electrons per half
            const int out = t >> 1, half = t & 1;
            const int spin = out >> 7, cc = out & 127, a_i = cc >> 2, d = cc & 3;
            const float ax = aposL[a_i*3+0], ay = aposL[a_i*3+1], az = aposL[a_i*3+2];
            float s = 0.f;
            #pragma unroll 8
            for (int q = 0; q < 32; ++q) {
                const int e = spin*64 + half*32 + q;
                float dx = rL[e*3+0]-ax, dy = rL[e*3+1]-ay, dz = rL[e*3+2]-az;
                float len = sqrtf(dx*dx + dy*dy + dz*dz);
                s += (d==0)?dx:(d==1)?dy:(d==2)?dz:len;
            }
            red[t] = s;
        }
        __syncthreads();
        if (t < 256) smL[t] = (red[2*t] + red[2*t+1]) * 0.015625f;
    } else {
        for (int idx = t; idx < 2*FS; idx += 512) {
            const int col = (idx < FS) ? idx : idx - FS;
            const int r0  = (idx < FS) ? 0 : 16;
            const float* base = psumIn + (size_t)r0*NSV + col;
            float s = 0.f;
            #pragma unroll
            for (int k = 0; k < 16; ++k) s += base[(size_t)k*NSV];
            smL[idx] = s * 0.015625f;
        }
    }
    __syncthreads();

    {   // t1 partials over 8 waves: t1[o] = Vb[o] + smean . Vw[0:2FS]
        constexpr int TI = (2*FS)/8;
        float a1 = 0.f;
        const float* Wp = Vw + (size_t)(wv*TI)*NSV + o;
        const float* mp = smL + wv*TI;
        #pragma unroll 8
        for (int k = 0; k < TI; ++k) a1 = fmaf(mp[k], Wp[(size_t)k*NSV], a1);
        red[wv*64 + ol] = a1;
    }
    __syncthreads();
    if (t < 64) {
        float s = Vb[o0 + t];
        #pragma unroll
        for (int g = 0; g < 8; ++g) s += red[g*64 + t];
        t1L[t] = s;
    }
    __syncthreads();

    const int e_l = wv & 3, kh = wv >> 2;
    {   // main GEMM, K split in halves across wave groups
        float a2 = (kh == 0) ? t1L[ol] : 0.f;
        const float* Ap = As + e_l*KP + kh*KP2;          // wave-uniform base
        const float* Wp = Vw + (size_t)(2*FS + kh*KP2)*NSV + o;
        #pragma unroll 16
        for (int k = 0; k < KP2; ++k)
            a2 = fmaf(Ap[k], Wp[(size_t)k*NSV], a2);
        red[wv*64 + ol] = a2;
    }
    __syncthreads();
    float v = 0.f;
    if (t < 256) {
        v = tanhf(red[(t>>6)*64 + (t&63)] + red[((t>>6)+4)*64 + (t&63)]);
        svOut[(size_t)(e0 + (t>>6))*NSV + o0 + (t&63)] = v;
    }
    if (psumOut) {
        __syncthreads();
        if (t < 256) red[t] = v;
        __syncthreads();
        if (t < 64) {
            float s = red[t] + red[64+t] + red[128+t] + red[192+t];
            psumOut[(size_t)et*NSV + o0 + t] = s;        // unscaled col sums
        }
    }
}

// ---------------------------------------------------------------------------
// heads + orbital matrices, per electron. 128 blocks x 512 threads.
// ---------------------------------------------------------------------------
__global__ __launch_bounds__(512)
void headsw_kernel(const float* __restrict__ svF,
                   const float* __restrict__ vhu_w, const float* __restrict__ vhu_b,
                   const float* __restrict__ vhd_w, const float* __restrict__ vhd_b,
                   const float* __restrict__ wu_w,  const float* __restrict__ wu_b,
                   const float* __restrict__ wd_w,  const float* __restrict__ wd_b,
                   const float* __restrict__ expv,  float* __restrict__ orb)
{
    __shared__ __align__(16) float row[512];
    __shared__ __align__(16) float redH[512];
    __shared__ __align__(16) float tmpL[256];
    const int e = blockIdx.x;
    const int spin = e >> 6;
    const int t = threadIdx.x;
    row[t] = svF[(size_t)e*NSV + t];
    __syncthreads();

    const float* W1 = spin ? vhd_w : vhu_w;
    const float* B1 = spin ? vhd_b : vhu_b;
    {
        const int o = t & 255, kc = t >> 8;       // kc in {0,1}
        float acc = kc ? 0.f : B1[o];
        const float* Wp = W1 + (size_t)(kc*256)*256 + o;
        const float* rp = row + kc*256;
        #pragma unroll 8
        for (int f = 0; f < 256; ++f)
            acc = fmaf(rp[f], Wp[(size_t)f*256], acc);
        redH[t] = acc;
    }
    __syncthreads();
    if (t < 256) tmpL[t] = redH[t] + redH[256 + t];
    __syncthreads();

    const float* W2 = spin ? wd_w : wu_w;
    const float* B2 = spin ? wd_b : wu_b;
    {
        const int o = t & 63, kc = t >> 6;        // kc in 0..7
        float acc = 0.f;
        const float* Wp = W2 + (size_t)(kc*32)*64 + o;
        const float* tp = tmpL + kc*32;
        #pragma unroll
        for (int f = 0; f < 32; ++f)
            acc = fmaf(tp[f], Wp[(size_t)f*64], acc);
        redH[kc*64 + o] = acc;
    }
    __syncthreads();
    if (t < 64) {
        float s = B2[t];
        #pragma unroll
        for (int g = 0; g < 8; ++g) s += redH[g*64 + t];
        orb[(size_t)e*64 + t] = s * expv[e];
    }
}

// ---------------------------------------------------------------------------
// det: two 64x64 log|det| via partial-pivot LU, one wave per matrix.
// DPP packed argmax, bit-cast v_readlane broadcasts, deferred log.
// ---------------------------------------------------------------------------
__device__ __forceinline__ int imax2(int a, int b) { return a > b ? a : b; }
__device__ __forceinline__ float readlane_f(float x, int lane) {
    return __int_as_float(__builtin_amdgcn_readlane(__float_as_int(x), lane));
}

__global__ __launch_bounds__(128)
void det_kernel(const float* __restrict__ orb, float* __restrict__ out)
{
    __shared__ float parts[2];
    const int t = threadIdx.x;
    const int w = t >> 6;
    const int lane = t & 63;
    const float* M = orb + (size_t)w*4096 + (size_t)lane*64;
    float rr[64];
    #pragma unroll
    for (int j = 0; j < 64; j += 4) {
        float4 v = *reinterpret_cast<const float4*>(M + j);
        rr[j]=v.x; rr[j+1]=v.y; rr[j+2]=v.z; rr[j+3]=v.w;
    }
    float pv_mine = 1.f;
    bool active = true;
    #pragma unroll
    for (int k = 0; k < 64; ++k) {
        int bits = (int)(__float_as_uint(rr[k]) & 0x7FFFFFC0u);
        int v = active ? (bits | lane) : lane;
        int tmp;
        tmp = __builtin_amdgcn_update_dpp(0, v, 0xB1,  0xF, 0xF, true); v = imax2(v, tmp);
        tmp = __builtin_amdgcn_update_dpp(0, v, 0x4E,  0xF, 0xF, true); v = imax2(v, tmp);
        tmp = __builtin_amdgcn_update_dpp(0, v, 0x141, 0xF, 0xF, true); v = imax2(v, tmp);
        tmp = __builtin_amdgcn_update_dpp(0, v, 0x140, 0xF, 0xF, true); v = imax2(v, tmp);
        tmp = __builtin_amdgcn_update_dpp(0, v, 0x142, 0xF, 0xF, true); v = imax2(v, tmp);
        tmp = __builtin_amdgcn_update_dpp(0, v, 0x143, 0xF, 0xF, true); v = imax2(v, tmp);
        const int idx = __builtin_amdgcn_readlane(v, 63) & 63;
        const float piv = readlane_f(rr[k], idx);
        pv_mine = (lane == k) ? piv : pv_mine;
        const float linv = __builtin_amdgcn_rcpf(piv);
        const float l = (active && lane != idx) ? rr[k]*linv : 0.f;
        if (lane == idx) active = false;
        #pragma unroll
        for (int j = k+1; j < 64; ++j)
            rr[j] = fmaf(-l, readlane_f(rr[j], idx), rr[j]);
    }
    float lg = logf(fabsf(pv_mine));
    #pragma unroll
    for (int off = 32; off; off >>= 1) lg += __shfl_down(lg, off);
    if (lane == 0) parts[w] = lg;
    __syncthreads();
    if (t == 0) out[0] = parts[0] + parts[1];
}

// ---------------------------------------------------------------------------
extern "C" void kernel_launch(void* const* d_in, const int* in_sizes, int n_in,
                              void* d_out, int out_size, void* d_ws, size_t ws_size,
                              hipStream_t stream)
{
    const float* r    = (const float*)d_in[0];
    const float* apos = (const float*)d_in[1];
    const float* V0w  = (const float*)d_in[2];
    const float* V0b  = (const float*)d_in[3];
    const float* W0w  = (const float*)d_in[4];
    const float* W0b  = (const float*)d_in[5];
    const float* V1w  = (const float*)d_in[6];
    const float* V1b  = (const float*)d_in[7];
    const float* W1w  = (const float*)d_in[8];
    const float* W1b  = (const float*)d_in[9];
    const float* V2w  = (const float*)d_in[10];
    const float* V2b  = (const float*)d_in[11];
    const float* W2w  = (const float*)d_in[12];
    const float* W2b  = (const float*)d_in[13];
    const float* afw  = (const float*)d_in[14];
    const float* afb  = (const float*)d_in[15];
    const float* vhuw = (const float*)d_in[16];
    const float* vhub = (const float*)d_in[17];
    const float* vhdw = (const float*)d_in[18];
    const float* vhdb = (const float*)d_in[19];
    const float* wuw  = (const float*)d_in[20];
    const float* wub  = (const float*)d_in[21];
    const float* wdw  = (const float*)d_in[22];
    const float* wdb  = (const float*)d_in[23];

    float* ws   = (float*)d_ws;
    float* sv0  = ws;              // 16384
    float* svA  = sv0  + 16384;    // 65536
    float* svB  = svA  + 65536;    // 65536
    float* expv = svB  + 65536;    // 128
    float* pme0 = expv + 128;      // 1024
    float* pme1 = pme0 + 1024;     // 16384
    float* pme2 = pme1 + 16384;    // 16384
    float* pme3 = pme2 + 16384;    // 16384
    float* psA  = pme3 + 16384;    // 16384
    float* psB  = psA  + 16384;    // 16384
    float* orb  = psB  + 16384;    // 8192

    // K1: pair chain, spin-split (256 blocks = full chip)
    pchain_kernel<<<256, 512, 0, stream>>>(r, apos, W0w, W0b, W1w, W1b, W2w, W2b,
                                           sv0, expv, pme0, pme1, pme2, pme3);
    // K2: A0 — smean from geometry
    a2_kernel<128, 4, true  ><<<256, 512, 0, stream>>>(sv0, pme0, nullptr, r, apos,
                                                       V0w, V0b, svA, psA);
    // K3: A1 — smean via psA
    a2_kernel<512, 64, false><<<256, 512, 0, stream>>>(svA, pme1, psA, r, apos,
                                                       V1w, V1b, svB, psB);
    // K4: A2 — smean via psB
    a2_kernel<512, 64, false><<<256, 512, 0, stream>>>(svB, pme2, psB, r, apos,
                                                       V2w, V2b, svA, psA);
    // K5: A3 (after-layer) — smean via psA
    a2_kernel<512, 64, false><<<256, 512, 0, stream>>>(svA, pme3, psA, r, apos,
                                                       afw, afb, svB, nullptr);
    // K6: heads + orbitals
    headsw_kernel<<<128, 512, 0, stream>>>(svB, vhuw, vhub, vhdw, vhdb,
                                           wuw, wub, wdw, wdb, expv, orb);
    // K7: determinants
    det_kernel<<<1, 128, 0, stream>>>(orb, (float*)d_out);
}

// Round 12
// 101.717 us; speedup vs baseline: 1.3631x; 1.0367x over previous
//
#include <hip/hip_runtime.h>
#include <math.h>

#define NSV 512

// ---------------------------------------------------------------------------
// K1 role A (blocks 0..255): pchain split by spin-half. Block b -> (j=b>>1,
// sp=b&1) owns rows i in [sp*64, sp*64+64) of pair-column j, fully in LDS.
// Emits pme1/2/3 spin-halves and expv[j] (sp=0). p never hits global memory.
// ---------------------------------------------------------------------------
__device__ void pchain_role(int b, const float* __restrict__ r,
                            const float* __restrict__ apos,
                            const float* __restrict__ W0w, const float* __restrict__ W0b,
                            const float* __restrict__ W1w, const float* __restrict__ W1b,
                            const float* __restrict__ W2w, const float* __restrict__ W2b,
                            float* __restrict__ expv,
                            float* __restrict__ pme1, float* __restrict__ pme2,
                            float* __restrict__ pme3, float* sh)
{
    float* rL    = sh;           // 384
    float* W0l   = sh + 384;     // 256
    float* aposL = sh + 640;     // 96
    float* shex  = sh + 736;     // 32
    float* p0c   = sh + 768;     // 64*4
    float* PA    = sh + 1024;    // 64*68 = 4352
    float* Wbuf  = sh + 5376;    // 4096
    const int j  = b >> 1, sp = b & 1;
    const int t  = threadIdx.x;
    const int i  = t >> 3;          // local row 0..63
    const int o0 = (t & 7) * 8;     // 8 outputs per thread

    if (t < 384) rL[t] = r[t];
    else if (t < 480) aposL[t - 384] = apos[t - 384];
    for (int idx = t; idx < 4096; idx += 512) Wbuf[idx] = W1w[idx];
    if (t < 256) W0l[t] = W0w[t];
    __syncthreads();

    const float rjx = rL[j*3+0], rjy = rL[j*3+1], rjz = rL[j*3+2];
    if (t < 64) {        // p0 rows sp*64+t of column j
        const int ii = sp*64 + t;
        float dx = rjx - rL[ii*3+0], dy = rjy - rL[ii*3+1], dz = rjz - rL[ii*3+2];
        float len = (ii == j) ? 0.f : sqrtf(dx*dx + dy*dy + dz*dz);
        p0c[t*4+0]=dx; p0c[t*4+1]=dy; p0c[t*4+2]=dz; p0c[t*4+3]=len;
    } else if (sp == 0 && t < 96) {   // exp terms for expv[j]
        const int k = t - 64;
        float dx = rjx - aposL[k*3+0], dy = rjy - aposL[k*3+1], dz = rjz - aposL[k*3+2];
        shex[k] = expf(-sqrtf(dx*dx + dy*dy + dz*dz));
    }
    __syncthreads();

    {   // layer0: PA[i][o] = tanh(p0c[i] @ W0 + b0), 8 outputs/thread
        const float x0=p0c[i*4+0], x1=p0c[i*4+1], x2=p0c[i*4+2], x3=p0c[i*4+3];
        #pragma unroll
        for (int k = 0; k < 8; ++k) {
            const int o = o0 + k;
            float a = W0b[o];
            a = fmaf(x0, W0l[o],     a);
            a = fmaf(x1, W0l[64+o],  a);
            a = fmaf(x2, W0l[128+o], a);
            a = fmaf(x3, W0l[192+o], a);
            PA[i*68+o] = tanhf(a);
        }
    }
    if (sp == 0 && t == 4) {
        float s = 0.f;
        #pragma unroll 8
        for (int k = 0; k < 32; ++k) s += shex[k];
        expv[j] = s;
    }
    __syncthreads();

    // pme1 spin-half + layer1 (W1, +res)
    if (t < 64) {
        float s = 0.f;
        #pragma unroll 8
        for (int k = 0; k < 64; ++k) s += PA[k*68 + t];
        pme1[j*128 + sp*64 + t] = s * 0.015625f;
    }
    float acc[8], res[8];
    const float* pa = PA + i*68;
    {
        #pragma unroll
        for (int k = 0; k < 8; ++k) acc[k] = W1b[o0+k];
        #pragma unroll 4
        for (int c = 0; c < 64; ++c) {
            const float av = pa[c];
            const float* wr = Wbuf + c*64 + o0;
            float4 wa = *reinterpret_cast<const float4*>(wr);
            float4 wb = *reinterpret_cast<const float4*>(wr+4);
            acc[0]=fmaf(av,wa.x,acc[0]); acc[1]=fmaf(av,wa.y,acc[1]);
            acc[2]=fmaf(av,wa.z,acc[2]); acc[3]=fmaf(av,wa.w,acc[3]);
            acc[4]=fmaf(av,wb.x,acc[4]); acc[5]=fmaf(av,wb.y,acc[5]);
            acc[6]=fmaf(av,wb.z,acc[6]); acc[7]=fmaf(av,wb.w,acc[7]);
        }
        #pragma unroll
        for (int k = 0; k < 8; ++k) res[k] = pa[o0+k];
    }
    __syncthreads();
    #pragma unroll
    for (int k = 0; k < 8; ++k) PA[i*68+o0+k] = tanhf(acc[k]) + res[k];
    __syncthreads();

    // pme2 spin-half + restage Wbuf = W2
    if (t < 64) {
        float s = 0.f;
        #pragma unroll 8
        for (int k = 0; k < 64; ++k) s += PA[k*68 + t];
        pme2[j*128 + sp*64 + t] = s * 0.015625f;
    }
    for (int idx = t; idx < 4096; idx += 512) Wbuf[idx] = W2w[idx];
    __syncthreads();

    {   // layer2 (W2, +res)
        #pragma unroll
        for (int k = 0; k < 8; ++k) acc[k] = W2b[o0+k];
        #pragma unroll 4
        for (int c = 0; c < 64; ++c) {
            const float av = pa[c];
            const float* wr = Wbuf + c*64 + o0;
            float4 wa = *reinterpret_cast<const float4*>(wr);
            float4 wb = *reinterpret_cast<const float4*>(wr+4);
            acc[0]=fmaf(av,wa.x,acc[0]); acc[1]=fmaf(av,wa.y,acc[1]);
            acc[2]=fmaf(av,wa.z,acc[2]); acc[3]=fmaf(av,wa.w,acc[3]);
            acc[4]=fmaf(av,wb.x,acc[4]); acc[5]=fmaf(av,wb.y,acc[5]);
            acc[6]=fmaf(av,wb.z,acc[6]); acc[7]=fmaf(av,wb.w,acc[7]);
        }
        #pragma unroll
        for (int k = 0; k < 8; ++k) res[k] = pa[o0+k];
    }
    __syncthreads();
    #pragma unroll
    for (int k = 0; k < 8; ++k) PA[i*68+o0+k] = tanhf(acc[k]) + res[k];
    __syncthreads();

    if (t < 64) {        // pme3 spin-half
        float s = 0.f;
        #pragma unroll 8
        for (int k = 0; k < 64; ++k) s += PA[k*68 + t];
        pme3[j*128 + sp*64 + t] = s * 0.015625f;
    }
}

// ---------------------------------------------------------------------------
// K1 role B (blocks 256..511): layer-0 s-GEMM, fully geometry-sourced —
// independent of pchain (pme0/sv0/smean0 all computed in-block from r,apos),
// which is what lets it share K1's dispatch with zero sync.
// Tile 4e x 64o (et=ab>>3, ot=ab&7). Emits svA + psA col-sum tiles.
// ---------------------------------------------------------------------------
__device__ void a0_role(int ab, const float* __restrict__ r,
                        const float* __restrict__ apos,
                        const float* __restrict__ V0w, const float* __restrict__ V0b,
                        float* __restrict__ svA, float* __restrict__ psA, float* sh)
{
    constexpr int KP = 136, KP2 = 68;
    float* As    = sh;           // 4*136 = 544
    float* smL   = sh + 544;     // 256
    float* red   = sh + 800;     // 512
    float* t1L   = sh + 1312;    // 64
    float* rL    = sh + 1376;    // 384
    float* aposL = sh + 1760;    // 96
    const int t  = threadIdx.x;
    const int et = ab >> 3, e0 = et * 4;
    const int o0 = (ab & 7) * 64;
    const int ol = t & 63, o = o0 + ol;
    const int wv = t >> 6;

    if (t < 384) rL[t] = r[t];
    else if (t < 480) aposL[t - 384] = apos[t - 384];
    __syncthreads();

    // As sv-part: 4 electrons x 32 atoms (t<128)
    if (t < 128) {
        const int e_l = t >> 5, k = t & 31;
        const int e = e0 + e_l;
        float dx = rL[e*3+0]-aposL[k*3+0], dy = rL[e*3+1]-aposL[k*3+1],
              dz = rL[e*3+2]-aposL[k*3+2];
        float len = sqrtf(dx*dx + dy*dy + dz*dz);
        float* dst = As + e_l*KP + 8 + k*4;
        dst[0]=dx; dst[1]=dy; dst[2]=dz; dst[3]=len;
    } else if (t < 160) {
        // As pme0-part: 4 electrons x 8 feats, each a 64-sum over geometry
        const int q = t - 128;
        const int e_l = q >> 3, outp = q & 7;
        const int spin = outp >> 2, c = outp & 3;
        const int e = e0 + e_l;
        const float ex = rL[e*3+0], ey = rL[e*3+1], ez = rL[e*3+2];
        float s = 0.f;
        for (int i2 = 0; i2 < 64; ++i2) {
            const int ii = spin*64 + i2;
            float dx = ex - rL[ii*3+0], dy = ey - rL[ii*3+1], dz = ez - rL[ii*3+2];
            float v = (c==0)?dx:(c==1)?dy:(c==2)?dz:
                      ((ii==e)?0.f:sqrtf(dx*dx+dy*dy+dz*dz));
            s += v;
        }
        As[e_l*KP + outp] = s * 0.015625f;
    }
    // smean0 from geometry: out = spin*128 + a_i*4 + d, two half-sums/thread
    {
        const int outp = t >> 1, half = t & 1;
        const int spin = outp >> 7, cc = outp & 127, a_i = cc >> 2, d = cc & 3;
        const float ax = aposL[a_i*3+0], ay = aposL[a_i*3+1], az = aposL[a_i*3+2];
        float s = 0.f;
        #pragma unroll 8
        for (int q = 0; q < 32; ++q) {
            const int e = spin*64 + half*32 + q;
            float dx = rL[e*3+0]-ax, dy = rL[e*3+1]-ay, dz = rL[e*3+2]-az;
            float len = sqrtf(dx*dx + dy*dy + dz*dz);
            s += (d==0)?dx:(d==1)?dy:(d==2)?dz:len;
        }
        red[t] = s;
    }
    __syncthreads();
    if (t < 256) smL[t] = (red[2*t] + red[2*t+1]) * 0.015625f;
    __syncthreads();

    {   // t1 partials over 8 waves: t1[o] = V0b[o] + smean0 . V0w[0:256]
        float a1 = 0.f;
        const float* Wp = V0w + (size_t)(wv*32)*NSV + o;
        const float* mp = smL + wv*32;
        #pragma unroll 8
        for (int k = 0; k < 32; ++k) a1 = fmaf(mp[k], Wp[(size_t)k*NSV], a1);
        red[wv*64 + ol] = a1;
    }
    __syncthreads();
    if (t < 64) {
        float s = V0b[o0 + t];
        #pragma unroll
        for (int g = 0; g < 8; ++g) s += red[g*64 + t];
        t1L[t] = s;
    }
    __syncthreads();

    const int e_l = wv & 3, kh = wv >> 2;
    {   // main GEMM: K=136 split in halves across wave groups
        float a2 = (kh == 0) ? t1L[ol] : 0.f;
        const float* Ap = As + e_l*KP + kh*KP2;
        const float* Wp = V0w + (size_t)(256 + kh*KP2)*NSV + o;
        #pragma unroll 16
        for (int k = 0; k < KP2; ++k)
            a2 = fmaf(Ap[k], Wp[(size_t)k*NSV], a2);
        red[wv*64 + ol] = a2;
    }
    __syncthreads();
    float v = 0.f;
    if (t < 256) {
        v = tanhf(red[(t>>6)*64 + (t&63)] + red[((t>>6)+4)*64 + (t&63)]);
        svA[(size_t)(e0 + (t>>6))*NSV + o0 + (t&63)] = v;
    }
    __syncthreads();
    if (t < 256) red[t] = v;
    __syncthreads();
    if (t < 64) {
        float s = red[t] + red[64+t] + red[128+t] + red[192+t];
        psA[(size_t)et*NSV + o0 + t] = s;            // unscaled col sums
    }
}

// ---------------------------------------------------------------------------
// K1: pchain (256 blocks) || A0 (256 blocks) — no inter-role dependency.
// ---------------------------------------------------------------------------
__global__ __launch_bounds__(512)
void front_kernel(const float* __restrict__ r, const float* __restrict__ apos,
                  const float* __restrict__ V0w, const float* __restrict__ V0b,
                  const float* __restrict__ W0w, const float* __restrict__ W0b,
                  const float* __restrict__ W1w, const float* __restrict__ W1b,
                  const float* __restrict__ W2w, const float* __restrict__ W2b,
                  float* __restrict__ svA, float* __restrict__ expv,
                  float* __restrict__ pme1, float* __restrict__ pme2,
                  float* __restrict__ pme3, float* __restrict__ psA)
{
    __shared__ __align__(16) float sh[9472];
    const int b = blockIdx.x;
    if (b < 256)
        pchain_role(b, r, apos, W0w, W0b, W1w, W1b, W2w, W2b,
                    expv, pme1, pme2, pme3, sh);
    else
        a0_role(b - 256, r, apos, V0w, V0b, svA, psA, sh);
}

// ---------------------------------------------------------------------------
// A kernel (layers 1..3): s-stream GEMM. 256 blocks x 512 threads, 4e x 64o.
// smean from psum tiles (16 rows per spin). Emits next psum unless last.
// ---------------------------------------------------------------------------
template<int FS, int FP>
__global__ __launch_bounds__(512)
void a2_kernel(const float* __restrict__ svIn, const float* __restrict__ pmeIn,
               const float* __restrict__ psumIn,
               const float* __restrict__ Vw, const float* __restrict__ Vb,
               float* __restrict__ svOut, float* __restrict__ psumOut)
{
    constexpr int KP  = 2*FP + FS;        // 640
    constexpr int KP2 = KP/2;
    __shared__ __align__(16) float As[4*KP];
    __shared__ __align__(16) float smL[2*FS];
    __shared__ __align__(16) float red[512];
    __shared__ float t1L[64];
    const int t  = threadIdx.x;
    const int et = blockIdx.x >> 3;
    const int e0 = et * 4;
    const int o0 = (blockIdx.x & 7) * 64;
    const int ol = t & 63;
    const int o  = o0 + ol;
    const int wv = t >> 6;                // 0..7

    for (int idx = t; idx < 4*2*FP; idx += 512)
        As[(idx/(2*FP))*KP + idx%(2*FP)] =
            pmeIn[(size_t)(e0 + idx/(2*FP))*(2*FP) + idx%(2*FP)];
    for (int idx = t; idx < FS; idx += 512) {     // 4 rows x FS/4 float4s
        const int row = idx / (FS/4), c4 = idx % (FS/4);
        *reinterpret_cast<float4*>(&As[row*KP + 2*FP + c4*4]) =
            *reinterpret_cast<const float4*>(&svIn[(size_t)(e0+row)*FS + c4*4]);
    }
    for (int idx = t; idx < 2*FS; idx += 512) {
        const int col = (idx < FS) ? idx : idx - FS;
        const int r0  = (idx < FS) ? 0 : 16;
        const float* base = psumIn + (size_t)r0*NSV + col;
        float s = 0.f;
        #pragma unroll
        for (int k = 0; k < 16; ++k) s += base[(size_t)k*NSV];
        smL[idx] = s * 0.015625f;
    }
    __syncthreads();

    {   // t1 partials over 8 waves: t1[o] = Vb[o] + smean . Vw[0:2FS]
        constexpr int TI = (2*FS)/8;
        float a1 = 0.f;
        const float* Wp = Vw + (size_t)(wv*TI)*NSV + o;
        const float* mp = smL + wv*TI;
        #pragma unroll 8
        for (int k = 0; k < TI; ++k) a1 = fmaf(mp[k], Wp[(size_t)k*NSV], a1);
        red[wv*64 + ol] = a1;
    }
    __syncthreads();
    if (t < 64) {
        float s = Vb[o0 + t];
        #pragma unroll
        for (int g = 0; g < 8; ++g) s += red[g*64 + t];
        t1L[t] = s;
    }
    __syncthreads();

    const int e_l = wv & 3, kh = wv >> 2;
    {   // main GEMM, K split in halves across wave groups
        float a2 = (kh == 0) ? t1L[ol] : 0.f;
        const float* Ap = As + e_l*KP + kh*KP2;          // wave-uniform base
        const float* Wp = Vw + (size_t)(2*FS + kh*KP2)*NSV + o;
        #pragma unroll 16
        for (int k = 0; k < KP2; ++k)
            a2 = fmaf(Ap[k], Wp[(size_t)k*NSV], a2);
        red[wv*64 + ol] = a2;
    }
    __syncthreads();
    float v = 0.f;
    if (t < 256) {
        v = tanhf(red[(t>>6)*64 + (t&63)] + red[((t>>6)+4)*64 + (t&63)]);
        svOut[(size_t)(e0 + (t>>6))*NSV + o0 + (t&63)] = v;
    }
    if (psumOut) {
        __syncthreads();
        if (t < 256) red[t] = v;
        __syncthreads();
        if (t < 64) {
            float s = red[t] + red[64+t] + red[128+t] + red[192+t];
            psumOut[(size_t)et*NSV + o0 + t] = s;        // unscaled col sums
        }
    }
}

// ---------------------------------------------------------------------------
// heads + orbital matrices, per electron. 128 blocks x 512 threads.
// ---------------------------------------------------------------------------
__global__ __launch_bounds__(512)
void headsw_kernel(const float* __restrict__ svF,
                   const float* __restrict__ vhu_w, const float* __restrict__ vhu_b,
                   const float* __restrict__ vhd_w, const float* __restrict__ vhd_b,
                   const float* __restrict__ wu_w,  const float* __restrict__ wu_b,
                   const float* __restrict__ wd_w,  const float* __restrict__ wd_b,
                   const float* __restrict__ expv,  float* __restrict__ orb)
{
    __shared__ __align__(16) float row[512];
    __shared__ __align__(16) float redH[512];
    __shared__ __align__(16) float tmpL[256];
    const int e = blockIdx.x;
    const int spin = e >> 6;
    const int t = threadIdx.x;
    row[t] = svF[(size_t)e*NSV + t];
    __syncthreads();

    const float* W1 = spin ? vhd_w : vhu_w;
    const float* B1 = spin ? vhd_b : vhu_b;
    {
        const int o = t & 255, kc = t >> 8;       // kc in {0,1}
        float acc = kc ? 0.f : B1[o];
        const float* Wp = W1 + (size_t)(kc*256)*256 + o;
        const float* rp = row + kc*256;
        #pragma unroll 8
        for (int f = 0; f < 256; ++f)
            acc = fmaf(rp[f], Wp[(size_t)f*256], acc);
        redH[t] = acc;
    }
    __syncthreads();
    if (t < 256) tmpL[t] = redH[t] + redH[256 + t];
    __syncthreads();

    const float* W2 = spin ? wd_w : wu_w;
    const float* B2 = spin ? wd_b : wu_b;
    {
        const int o = t & 63, kc = t >> 6;        // kc in 0..7
        float acc = 0.f;
        const float* Wp = W2 + (size_t)(kc*32)*64 + o;
        const float* tp = tmpL + kc*32;
        #pragma unroll
        for (int f = 0; f < 32; ++f)
            acc = fmaf(tp[f], Wp[(size_t)f*64], acc);
        redH[kc*64 + o] = acc;
    }
    __syncthreads();
    if (t < 64) {
        float s = B2[t];
        #pragma unroll
        for (int g = 0; g < 8; ++g) s += redH[g*64 + t];
        orb[(size_t)e*64 + t] = s * expv[e];
    }
}

// ---------------------------------------------------------------------------
// det: two 64x64 log|det| via partial-pivot LU, one wave per matrix.
// DPP packed argmax, bit-cast v_readlane broadcasts, deferred log.
// ---------------------------------------------------------------------------
__device__ __forceinline__ int imax2(int a, int b) { return a > b ? a : b; }
__device__ __forceinline__ float readlane_f(float x, int lane) {
    return __int_as_float(__builtin_amdgcn_readlane(__float_as_int(x), lane));
}

__global__ __launch_bounds__(128)
void det_kernel(const float* __restrict__ orb, float* __restrict__ out)
{
    __shared__ float parts[2];
    const int t = threadIdx.x;
    const int w = t >> 6;
    const int lane = t & 63;
    const float* M = orb + (size_t)w*4096 + (size_t)lane*64;
    float rr[64];
    #pragma unroll
    for (int j = 0; j < 64; j += 4) {
        float4 v = *reinterpret_cast<const float4*>(M + j);
        rr[j]=v.x; rr[j+1]=v.y; rr[j+2]=v.z; rr[j+3]=v.w;
    }
    float pv_mine = 1.f;
    bool active = true;
    #pragma unroll
    for (int k = 0; k < 64; ++k) {
        int bits = (int)(__float_as_uint(rr[k]) & 0x7FFFFFC0u);
        int v = active ? (bits | lane) : lane;
        int tmp;
        tmp = __builtin_amdgcn_update_dpp(0, v, 0xB1,  0xF, 0xF, true); v = imax2(v, tmp);
        tmp = __builtin_amdgcn_update_dpp(0, v, 0x4E,  0xF, 0xF, true); v = imax2(v, tmp);
        tmp = __builtin_amdgcn_update_dpp(0, v, 0x141, 0xF, 0xF, true); v = imax2(v, tmp);
        tmp = __builtin_amdgcn_update_dpp(0, v, 0x140, 0xF, 0xF, true); v = imax2(v, tmp);
        tmp = __builtin_amdgcn_update_dpp(0, v, 0x142, 0xF, 0xF, true); v = imax2(v, tmp);
        tmp = __builtin_amdgcn_update_dpp(0, v, 0x143, 0xF, 0xF, true); v = imax2(v, tmp);
        const int idx = __builtin_amdgcn_readlane(v, 63) & 63;
        const float piv = readlane_f(rr[k], idx);
        pv_mine = (lane == k) ? piv : pv_mine;
        const float linv = __builtin_amdgcn_rcpf(piv);
        const float l = (active && lane != idx) ? rr[k]*linv : 0.f;
        if (lane == idx) active = false;
        #pragma unroll
        for (int j = k+1; j < 64; ++j)
            rr[j] = fmaf(-l, readlane_f(rr[j], idx), rr[j]);
    }
    float lg = logf(fabsf(pv_mine));
    #pragma unroll
    for (int off = 32; off; off >>= 1) lg += __shfl_down(lg, off);
    if (lane == 0) parts[w] = lg;
    __syncthreads();
    if (t == 0) out[0] = parts[0] + parts[1];
}

// ---------------------------------------------------------------------------
extern "C" void kernel_launch(void* const* d_in, const int* in_sizes, int n_in,
                              void* d_out, int out_size, void* d_ws, size_t ws_size,
                              hipStream_t stream)
{
    const float* r    = (const float*)d_in[0];
    const float* apos = (const float*)d_in[1];
    const float* V0w  = (const float*)d_in[2];
    const float* V0b  = (const float*)d_in[3];
    const float* W0w  = (const float*)d_in[4];
    const float* W0b  = (const float*)d_in[5];
    const float* V1w  = (const float*)d_in[6];
    const float* V1b  = (const float*)d_in[7];
    const float* W1w  = (const float*)d_in[8];
    const float* W1b  = (const float*)d_in[9];
    const float* V2w  = (const float*)d_in[10];
    const float* V2b  = (const float*)d_in[11];
    const float* W2w  = (const float*)d_in[12];
    const float* W2b  = (const float*)d_in[13];
    const float* afw  = (const float*)d_in[14];
    const float* afb  = (const float*)d_in[15];
    const float* vhuw = (const float*)d_in[16];
    const float* vhub = (const float*)d_in[17];
    const float* vhdw = (const float*)d_in[18];
    const float* vhdb = (const float*)d_in[19];
    const float* wuw  = (const float*)d_in[20];
    const float* wub  = (const float*)d_in[21];
    const float* wdw  = (const float*)d_in[22];
    const float* wdb  = (const float*)d_in[23];

    float* ws   = (float*)d_ws;
    float* svA  = ws;              // 65536
    float* svB  = svA  + 65536;    // 65536
    float* expv = svB  + 65536;    // 128
    float* pme1 = expv + 128;      // 16384
    float* pme2 = pme1 + 16384;    // 16384
    float* pme3 = pme2 + 16384;    // 16384
    float* psA  = pme3 + 16384;    // 16384
    float* psB  = psA  + 16384;    // 16384
    float* orb  = psB  + 16384;    // 8192

    // K1: pchain (256 blocks) || A0 (256 blocks) — independent roles
    front_kernel<<<512, 512, 0, stream>>>(r, apos, V0w, V0b, W0w, W0b,
                                          W1w, W1b, W2w, W2b,
                                          svA, expv, pme1, pme2, pme3, psA);
    // K2: A1 — smean via psA
    a2_kernel<512, 64><<<256, 512, 0, stream>>>(svA, pme1, psA, V1w, V1b, svB, psB);
    // K3: A2 — smean via psB
    a2_kernel<512, 64><<<256, 512, 0, stream>>>(svB, pme2, psB, V2w, V2b, svA, psA);
    // K4: A3 (after-layer) — smean via psA
    a2_kernel<512, 64><<<256, 512, 0, stream>>>(svA, pme3, psA, afw, afb, svB, nullptr);
    // K5: heads + orbitals
    headsw_kernel<<<128, 512, 0, stream>>>(svB, vhuw, vhub, vhdw, vhdb,
                                           wuw, wub, wdw, wdb, expv, orb);
    // K6: determinants
    det_kernel<<<1, 128, 0, stream>>>(orb, (float*)d_out);
}

// Round 13
// 91.682 us; speedup vs baseline: 1.5123x; 1.1095x over previous
//
#include <hip/hip_runtime.h>
#include <math.h>

#define NSV 512

// ---------------------------------------------------------------------------
// K1 role A (blocks 0..255): pchain split by spin-half (proven R11/R12).
// ---------------------------------------------------------------------------
__device__ void pchain_role(int b, const float* __restrict__ r,
                            const float* __restrict__ apos,
                            const float* __restrict__ W0w, const float* __restrict__ W0b,
                            const float* __restrict__ W1w, const float* __restrict__ W1b,
                            const float* __restrict__ W2w, const float* __restrict__ W2b,
                            float* __restrict__ expv,
                            float* __restrict__ pme1, float* __restrict__ pme2,
                            float* __restrict__ pme3, float* sh)
{
    float* rL    = sh;           // 384
    float* W0l   = sh + 384;     // 256
    float* aposL = sh + 640;     // 96
    float* shex  = sh + 736;     // 32
    float* p0c   = sh + 768;     // 64*4
    float* PA    = sh + 1024;    // 64*68 = 4352
    float* Wbuf  = sh + 5376;    // 4096
    const int j  = b >> 1, sp = b & 1;
    const int t  = threadIdx.x;
    const int i  = t >> 3;          // local row 0..63
    const int o0 = (t & 7) * 8;     // 8 outputs per thread

    if (t < 384) rL[t] = r[t];
    else if (t < 480) aposL[t - 384] = apos[t - 384];
    for (int idx = t; idx < 4096; idx += 512) Wbuf[idx] = W1w[idx];
    if (t < 256) W0l[t] = W0w[t];
    __syncthreads();

    const float rjx = rL[j*3+0], rjy = rL[j*3+1], rjz = rL[j*3+2];
    if (t < 64) {        // p0 rows sp*64+t of column j
        const int ii = sp*64 + t;
        float dx = rjx - rL[ii*3+0], dy = rjy - rL[ii*3+1], dz = rjz - rL[ii*3+2];
        float len = (ii == j) ? 0.f : sqrtf(dx*dx + dy*dy + dz*dz);
        p0c[t*4+0]=dx; p0c[t*4+1]=dy; p0c[t*4+2]=dz; p0c[t*4+3]=len;
    } else if (sp == 0 && t < 96) {   // exp terms for expv[j]
        const int k = t - 64;
        float dx = rjx - aposL[k*3+0], dy = rjy - aposL[k*3+1], dz = rjz - aposL[k*3+2];
        shex[k] = expf(-sqrtf(dx*dx + dy*dy + dz*dz));
    }
    __syncthreads();

    {   // layer0: PA[i][o] = tanh(p0c[i] @ W0 + b0), 8 outputs/thread
        const float x0=p0c[i*4+0], x1=p0c[i*4+1], x2=p0c[i*4+2], x3=p0c[i*4+3];
        #pragma unroll
        for (int k = 0; k < 8; ++k) {
            const int o = o0 + k;
            float a = W0b[o];
            a = fmaf(x0, W0l[o],     a);
            a = fmaf(x1, W0l[64+o],  a);
            a = fmaf(x2, W0l[128+o], a);
            a = fmaf(x3, W0l[192+o], a);
            PA[i*68+o] = tanhf(a);
        }
    }
    if (sp == 0 && t == 4) {
        float s = 0.f;
        #pragma unroll 8
        for (int k = 0; k < 32; ++k) s += shex[k];
        expv[j] = s;
    }
    __syncthreads();

    // pme1 spin-half + layer1 (W1, +res)
    if (t < 64) {
        float s = 0.f;
        #pragma unroll 8
        for (int k = 0; k < 64; ++k) s += PA[k*68 + t];
        pme1[j*128 + sp*64 + t] = s * 0.015625f;
    }
    float acc[8], res[8];
    const float* pa = PA + i*68;
    {
        #pragma unroll
        for (int k = 0; k < 8; ++k) acc[k] = W1b[o0+k];
        #pragma unroll 4
        for (int c = 0; c < 64; ++c) {
            const float av = pa[c];
            const float* wr = Wbuf + c*64 + o0;
            float4 wa = *reinterpret_cast<const float4*>(wr);
            float4 wb = *reinterpret_cast<const float4*>(wr+4);
            acc[0]=fmaf(av,wa.x,acc[0]); acc[1]=fmaf(av,wa.y,acc[1]);
            acc[2]=fmaf(av,wa.z,acc[2]); acc[3]=fmaf(av,wa.w,acc[3]);
            acc[4]=fmaf(av,wb.x,acc[4]); acc[5]=fmaf(av,wb.y,acc[5]);
            acc[6]=fmaf(av,wb.z,acc[6]); acc[7]=fmaf(av,wb.w,acc[7]);
        }
        #pragma unroll
        for (int k = 0; k < 8; ++k) res[k] = pa[o0+k];
    }
    __syncthreads();
    #pragma unroll
    for (int k = 0; k < 8; ++k) PA[i*68+o0+k] = tanhf(acc[k]) + res[k];
    __syncthreads();

    // pme2 spin-half + restage Wbuf = W2
    if (t < 64) {
        float s = 0.f;
        #pragma unroll 8
        for (int k = 0; k < 64; ++k) s += PA[k*68 + t];
        pme2[j*128 + sp*64 + t] = s * 0.015625f;
    }
    for (int idx = t; idx < 4096; idx += 512) Wbuf[idx] = W2w[idx];
    __syncthreads();

    {   // layer2 (W2, +res)
        #pragma unroll
        for (int k = 0; k < 8; ++k) acc[k] = W2b[o0+k];
        #pragma unroll 4
        for (int c = 0; c < 64; ++c) {
            const float av = pa[c];
            const float* wr = Wbuf + c*64 + o0;
            float4 wa = *reinterpret_cast<const float4*>(wr);
            float4 wb = *reinterpret_cast<const float4*>(wr+4);
            acc[0]=fmaf(av,wa.x,acc[0]); acc[1]=fmaf(av,wa.y,acc[1]);
            acc[2]=fmaf(av,wa.z,acc[2]); acc[3]=fmaf(av,wa.w,acc[3]);
            acc[4]=fmaf(av,wb.x,acc[4]); acc[5]=fmaf(av,wb.y,acc[5]);
            acc[6]=fmaf(av,wb.z,acc[6]); acc[7]=fmaf(av,wb.w,acc[7]);
        }
        #pragma unroll
        for (int k = 0; k < 8; ++k) res[k] = pa[o0+k];
    }
    __syncthreads();
    #pragma unroll
    for (int k = 0; k < 8; ++k) PA[i*68+o0+k] = tanhf(acc[k]) + res[k];
    __syncthreads();

    if (t < 64) {        // pme3 spin-half
        float s = 0.f;
        #pragma unroll 8
        for (int k = 0; k < 64; ++k) s += PA[k*68 + t];
        pme3[j*128 + sp*64 + t] = s * 0.015625f;
    }
}

// ---------------------------------------------------------------------------
// K1 role B (blocks 256..511): layer-0 s-GEMM, geometry-sourced (R12-proven).
// ---------------------------------------------------------------------------
__device__ void a0_role(int ab, const float* __restrict__ r,
                        const float* __restrict__ apos,
                        const float* __restrict__ V0w, const float* __restrict__ V0b,
                        float* __restrict__ svA, float* __restrict__ psA, float* sh)
{
    constexpr int KP = 136, KP2 = 68;
    float* As    = sh;           // 544
    float* smL   = sh + 544;     // 256
    float* red   = sh + 800;     // 512
    float* t1L   = sh + 1312;    // 64
    float* rL    = sh + 1376;    // 384
    float* aposL = sh + 1760;    // 96
    const int t  = threadIdx.x;
    const int et = ab >> 3, e0 = et * 4;
    const int o0 = (ab & 7) * 64;
    const int ol = t & 63, o = o0 + ol;
    const int wv = t >> 6;

    if (t < 384) rL[t] = r[t];
    else if (t < 480) aposL[t - 384] = apos[t - 384];
    __syncthreads();

    if (t < 128) {       // As sv-part: 4 electrons x 32 atoms
        const int e_l = t >> 5, k = t & 31;
        const int e = e0 + e_l;
        float dx = rL[e*3+0]-aposL[k*3+0], dy = rL[e*3+1]-aposL[k*3+1],
              dz = rL[e*3+2]-aposL[k*3+2];
        float len = sqrtf(dx*dx + dy*dy + dz*dz);
        float* dst = As + e_l*KP + 8 + k*4;
        dst[0]=dx; dst[1]=dy; dst[2]=dz; dst[3]=len;
    } else if (t < 160) { // As pme0-part: 4 electrons x 8 feats
        const int q = t - 128;
        const int e_l = q >> 3, outp = q & 7;
        const int spin = outp >> 2, c = outp & 3;
        const int e = e0 + e_l;
        const float ex = rL[e*3+0], ey = rL[e*3+1], ez = rL[e*3+2];
        float s = 0.f;
        for (int i2 = 0; i2 < 64; ++i2) {
            const int ii = spin*64 + i2;
            float dx = ex - rL[ii*3+0], dy = ey - rL[ii*3+1], dz = ez - rL[ii*3+2];
            float v = (c==0)?dx:(c==1)?dy:(c==2)?dz:
                      ((ii==e)?0.f:sqrtf(dx*dx+dy*dy+dz*dz));
            s += v;
        }
        As[e_l*KP + outp] = s * 0.015625f;
    }
    {   // smean0 from geometry: two half-sums per thread
        const int outp = t >> 1, half = t & 1;
        const int spin = outp >> 7, cc = outp & 127, a_i = cc >> 2, d = cc & 3;
        const float ax = aposL[a_i*3+0], ay = aposL[a_i*3+1], az = aposL[a_i*3+2];
        float s = 0.f;
        #pragma unroll 8
        for (int q = 0; q < 32; ++q) {
            const int e = spin*64 + half*32 + q;
            float dx = rL[e*3+0]-ax, dy = rL[e*3+1]-ay, dz = rL[e*3+2]-az;
            float len = sqrtf(dx*dx + dy*dy + dz*dz);
            s += (d==0)?dx:(d==1)?dy:(d==2)?dz:len;
        }
        red[t] = s;
    }
    __syncthreads();
    if (t < 256) smL[t] = (red[2*t] + red[2*t+1]) * 0.015625f;
    __syncthreads();

    {   // t1 partials over 8 waves
        float a1 = 0.f;
        const float* Wp = V0w + (size_t)(wv*32)*NSV + o;
        const float* mp = smL + wv*32;
        #pragma unroll 8
        for (int k = 0; k < 32; ++k) a1 = fmaf(mp[k], Wp[(size_t)k*NSV], a1);
        red[wv*64 + ol] = a1;
    }
    __syncthreads();
    if (t < 64) {
        float s = V0b[o0 + t];
        #pragma unroll
        for (int g = 0; g < 8; ++g) s += red[g*64 + t];
        t1L[t] = s;
    }
    __syncthreads();

    const int e_l = wv & 3, kh = wv >> 2;
    {
        float a2 = (kh == 0) ? t1L[ol] : 0.f;
        const float* Ap = As + e_l*KP + kh*KP2;
        const float* Wp = V0w + (size_t)(256 + kh*KP2)*NSV + o;
        #pragma unroll 16
        for (int k = 0; k < KP2; ++k)
            a2 = fmaf(Ap[k], Wp[(size_t)k*NSV], a2);
        red[wv*64 + ol] = a2;
    }
    __syncthreads();
    float v = 0.f;
    if (t < 256) {
        v = tanhf(red[(t>>6)*64 + (t&63)] + red[((t>>6)+4)*64 + (t&63)]);
        svA[(size_t)(e0 + (t>>6))*NSV + o0 + (t&63)] = v;
    }
    __syncthreads();
    if (t < 256) red[t] = v;
    __syncthreads();
    if (t < 64) {
        float s = red[t] + red[64+t] + red[128+t] + red[192+t];
        psA[(size_t)et*NSV + o0 + t] = s;
    }
}

// ---------------------------------------------------------------------------
// K1 role C (blocks 512..575): C = vh @ wu  (512x64 per spin), LDS-chunked.
// Heads have NO nonlinearity -> orb = svB @ C + cb is exact.
// ---------------------------------------------------------------------------
__device__ void headc_role(int g, const float* __restrict__ vh,
                           const float* __restrict__ wu,
                           float* __restrict__ Cdst, float* sh)
{
    float* wuL = sh;          // 4096
    float* vhL = sh + 4096;   // 1024
    const int t = threadIdx.x;
    const int o2 = t & 63, wq = t >> 6;      // wq 0..7
    const int f0 = g * 16;
    float a0 = 0.f, a1 = 0.f;
    for (int hc = 0; hc < 4; ++hc) {
        __syncthreads();
        for (int idx = t; idx < 4096; idx += 512)
            wuL[idx] = wu[(size_t)(hc*64 + (idx>>6))*64 + (idx&63)];
        for (int idx = t; idx < 1024; idx += 512)
            vhL[idx] = vh[(size_t)(f0 + (idx>>6))*256 + hc*64 + (idx&63)];
        __syncthreads();
        #pragma unroll 8
        for (int h = 0; h < 64; ++h) {
            const float wuv = wuL[h*64 + o2];
            a0 = fmaf(vhL[wq*64 + h],     wuv, a0);
            a1 = fmaf(vhL[(wq+8)*64 + h], wuv, a1);
        }
    }
    Cdst[(size_t)(f0 + wq)*64 + o2]     = a0;
    Cdst[(size_t)(f0 + wq + 8)*64 + o2] = a1;
}

// K1 role D (blocks 576..577): cb = vhb @ wu + wub  (64 per spin).
__device__ void cb_role(const float* __restrict__ vhb, const float* __restrict__ wu,
                        const float* __restrict__ wub, float* __restrict__ cbdst,
                        float* sh)
{
    const int t = threadIdx.x;
    const int o2 = t & 63, wq = t >> 6;
    float acc = 0.f;
    #pragma unroll
    for (int k = 0; k < 32; ++k) {
        const int h = wq*32 + k;
        acc = fmaf(vhb[h], wu[(size_t)h*64 + o2], acc);
    }
    sh[t] = acc;
    __syncthreads();
    if (t < 64) {
        float s = wub[t];
        #pragma unroll
        for (int g = 0; g < 8; ++g) s += sh[g*64 + t];
        cbdst[t] = s;
    }
}

// ---------------------------------------------------------------------------
// K1: pchain(256) || A0(256) || headC(64) || cb(2) — all independent roles.
// ---------------------------------------------------------------------------
__global__ __launch_bounds__(512)
void front_kernel(const float* __restrict__ r, const float* __restrict__ apos,
                  const float* __restrict__ V0w, const float* __restrict__ V0b,
                  const float* __restrict__ W0w, const float* __restrict__ W0b,
                  const float* __restrict__ W1w, const float* __restrict__ W1b,
                  const float* __restrict__ W2w, const float* __restrict__ W2b,
                  const float* __restrict__ vhuw, const float* __restrict__ vhub,
                  const float* __restrict__ vhdw, const float* __restrict__ vhdb,
                  const float* __restrict__ wuw,  const float* __restrict__ wub,
                  const float* __restrict__ wdw,  const float* __restrict__ wdb,
                  float* __restrict__ svA, float* __restrict__ expv,
                  float* __restrict__ pme1, float* __restrict__ pme2,
                  float* __restrict__ pme3, float* __restrict__ psA,
                  float* __restrict__ Cmat, float* __restrict__ cb)
{
    __shared__ __align__(16) float sh[9472];
    const int b = blockIdx.x;
    if (b < 256) {
        pchain_role(b, r, apos, W0w, W0b, W1w, W1b, W2w, W2b,
                    expv, pme1, pme2, pme3, sh);
    } else if (b < 512) {
        a0_role(b - 256, r, apos, V0w, V0b, svA, psA, sh);
    } else if (b < 576) {
        const int g = b - 512;
        const int spin = g >> 5;
        headc_role(g & 31, spin ? vhdw : vhuw, spin ? wdw : wuw,
                   Cmat + (size_t)spin*32768, sh);
    } else {
        const int spin = b - 576;
        cb_role(spin ? vhdb : vhub, spin ? wdw : wuw, spin ? wdb : wub,
                cb + spin*64, sh);
    }
}

// ---------------------------------------------------------------------------
// A kernel (layers 1,2): s-stream GEMM (R12-proven). Grid 256 (+1 for K2:
// block 256 initializes orb = cb broadcast — cross-dispatch-safe role).
// ---------------------------------------------------------------------------
template<int FS, int FP>
__global__ __launch_bounds__(512)
void a2_kernel(const float* __restrict__ svIn, const float* __restrict__ pmeIn,
               const float* __restrict__ psumIn,
               const float* __restrict__ Vw, const float* __restrict__ Vb,
               float* __restrict__ svOut, float* __restrict__ psumOut,
               float* __restrict__ orbInit, const float* __restrict__ cb)
{
    constexpr int KP  = 2*FP + FS;        // 640
    constexpr int KP2 = KP/2;
    __shared__ __align__(16) float As[4*KP];
    __shared__ __align__(16) float smL[2*FS];
    __shared__ __align__(16) float red[512];
    __shared__ float t1L[64];
    const int t  = threadIdx.x;
    if (blockIdx.x >= 256) {             // orb-init role (K2 only)
        for (int idx = t; idx < 8192; idx += 512)
            orbInit[idx] = cb[(((idx >> 6) >> 6) << 6) + (idx & 63)];
        return;
    }
    const int et = blockIdx.x >> 3;
    const int e0 = et * 4;
    const int o0 = (blockIdx.x & 7) * 64;
    const int ol = t & 63;
    const int o  = o0 + ol;
    const int wv = t >> 6;

    for (int idx = t; idx < 4*2*FP; idx += 512)
        As[(idx/(2*FP))*KP + idx%(2*FP)] =
            pmeIn[(size_t)(e0 + idx/(2*FP))*(2*FP) + idx%(2*FP)];
    for (int idx = t; idx < FS; idx += 512) {
        const int row = idx / (FS/4), c4 = idx % (FS/4);
        *reinterpret_cast<float4*>(&As[row*KP + 2*FP + c4*4]) =
            *reinterpret_cast<const float4*>(&svIn[(size_t)(e0+row)*FS + c4*4]);
    }
    for (int idx = t; idx < 2*FS; idx += 512) {
        const int col = (idx < FS) ? idx : idx - FS;
        const int r0  = (idx < FS) ? 0 : 16;
        const float* base = psumIn + (size_t)r0*NSV + col;
        float s = 0.f;
        #pragma unroll
        for (int k = 0; k < 16; ++k) s += base[(size_t)k*NSV];
        smL[idx] = s * 0.015625f;
    }
    __syncthreads();

    {
        constexpr int TI = (2*FS)/8;
        float a1 = 0.f;
        const float* Wp = Vw + (size_t)(wv*TI)*NSV + o;
        const float* mp = smL + wv*TI;
        #pragma unroll 8
        for (int k = 0; k < TI; ++k) a1 = fmaf(mp[k], Wp[(size_t)k*NSV], a1);
        red[wv*64 + ol] = a1;
    }
    __syncthreads();
    if (t < 64) {
        float s = Vb[o0 + t];
        #pragma unroll
        for (int g = 0; g < 8; ++g) s += red[g*64 + t];
        t1L[t] = s;
    }
    __syncthreads();

    const int e_l = wv & 3, kh = wv >> 2;
    {
        float a2 = (kh == 0) ? t1L[ol] : 0.f;
        const float* Ap = As + e_l*KP + kh*KP2;
        const float* Wp = Vw + (size_t)(2*FS + kh*KP2)*NSV + o;
        #pragma unroll 16
        for (int k = 0; k < KP2; ++k)
            a2 = fmaf(Ap[k], Wp[(size_t)k*NSV], a2);
        red[wv*64 + ol] = a2;
    }
    __syncthreads();
    float v = 0.f;
    if (t < 256) {
        v = tanhf(red[(t>>6)*64 + (t&63)] + red[((t>>6)+4)*64 + (t&63)]);
        svOut[(size_t)(e0 + (t>>6))*NSV + o0 + (t&63)] = v;
    }
    if (psumOut) {
        __syncthreads();
        if (t < 256) red[t] = v;
        __syncthreads();
        if (t < 64) {
            float s = red[t] + red[64+t] + red[128+t] + red[192+t];
            psumOut[(size_t)et*NSV + o0 + t] = s;
        }
    }
}

// ---------------------------------------------------------------------------
// K4: A3 + heads fused. Same a2 body (afw), but svB tile is consumed
// in-block: orb[e][o2] += sum_f svB_tile[e][f] * C[o0+f][o2] via atomicAdd.
// svB never hits global memory; heads dispatch eliminated.
// ---------------------------------------------------------------------------
__global__ __launch_bounds__(512)
void a3h_kernel(const float* __restrict__ svIn, const float* __restrict__ pmeIn,
                const float* __restrict__ psumIn,
                const float* __restrict__ Vw, const float* __restrict__ Vb,
                const float* __restrict__ Cmat, float* __restrict__ orb)
{
    constexpr int FS = 512, FP = 64;
    constexpr int KP  = 2*FP + FS;        // 640
    constexpr int KP2 = KP/2;
    __shared__ __align__(16) float As[4*KP];
    __shared__ __align__(16) float smL[2*FS];
    __shared__ __align__(16) float red[512];
    __shared__ float t1L[64];
    const int t  = threadIdx.x;
    const int et = blockIdx.x >> 3;
    const int e0 = et * 4;
    const int o0 = (blockIdx.x & 7) * 64;
    const int ol = t & 63;
    const int o  = o0 + ol;
    const int wv = t >> 6;

    for (int idx = t; idx < 4*2*FP; idx += 512)
        As[(idx/(2*FP))*KP + idx%(2*FP)] =
            pmeIn[(size_t)(e0 + idx/(2*FP))*(2*FP) + idx%(2*FP)];
    for (int idx = t; idx < FS; idx += 512) {
        const int row = idx / (FS/4), c4 = idx % (FS/4);
        *reinterpret_cast<float4*>(&As[row*KP + 2*FP + c4*4]) =
            *reinterpret_cast<const float4*>(&svIn[(size_t)(e0+row)*FS + c4*4]);
    }
    for (int idx = t; idx < 2*FS; idx += 512) {
        const int col = (idx < FS) ? idx : idx - FS;
        const int r0  = (idx < FS) ? 0 : 16;
        const float* base = psumIn + (size_t)r0*NSV + col;
        float s = 0.f;
        #pragma unroll
        for (int k = 0; k < 16; ++k) s += base[(size_t)k*NSV];
        smL[idx] = s * 0.015625f;
    }
    __syncthreads();

    {
        constexpr int TI = (2*FS)/8;
        float a1 = 0.f;
        const float* Wp = Vw + (size_t)(wv*TI)*NSV + o;
        const float* mp = smL + wv*TI;
        #pragma unroll 8
        for (int k = 0; k < TI; ++k) a1 = fmaf(mp[k], Wp[(size_t)k*NSV], a1);
        red[wv*64 + ol] = a1;
    }
    __syncthreads();
    if (t < 64) {
        float s = Vb[o0 + t];
        #pragma unroll
        for (int g = 0; g < 8; ++g) s += red[g*64 + t];
        t1L[t] = s;
    }
    __syncthreads();

    const int e_l = wv & 3, kh = wv >> 2;
    {
        float a2 = (kh == 0) ? t1L[ol] : 0.f;
        const float* Ap = As + e_l*KP + kh*KP2;
        const float* Wp = Vw + (size_t)(2*FS + kh*KP2)*NSV + o;
        #pragma unroll 16
        for (int k = 0; k < KP2; ++k)
            a2 = fmaf(Ap[k], Wp[(size_t)k*NSV], a2);
        red[wv*64 + ol] = a2;
    }
    __syncthreads();
    float v = 0.f;
    if (t < 256)
        v = tanhf(red[(t>>6)*64 + (t&63)] + red[((t>>6)+4)*64 + (t&63)]);
    __syncthreads();
    if (t < 256) smL[t] = v;              // svB tile [4e][64f], f = o0+local
    __syncthreads();
    if (t < 256) {
        const int el2 = t >> 6, o2 = t & 63;
        const int spin = et >> 4;
        const float* Cp = Cmat + (size_t)spin*32768 + (size_t)o0*64 + o2;
        const float* sp = smL + el2*64;
        float acc = 0.f;
        #pragma unroll 8
        for (int f = 0; f < 64; ++f)
            acc = fmaf(sp[f], Cp[(size_t)f*64], acc);
        atomicAdd(&orb[(size_t)(e0 + el2)*64 + o2], acc);
    }
}

// ---------------------------------------------------------------------------
// det: two 64x64 log|det| LU; expv row-scale applied at load (was headsw's).
// ---------------------------------------------------------------------------
__device__ __forceinline__ int imax2(int a, int b) { return a > b ? a : b; }
__device__ __forceinline__ float readlane_f(float x, int lane) {
    return __int_as_float(__builtin_amdgcn_readlane(__float_as_int(x), lane));
}

__global__ __launch_bounds__(128)
void det_kernel(const float* __restrict__ orb, const float* __restrict__ expv,
                float* __restrict__ out)
{
    __shared__ float parts[2];
    const int t = threadIdx.x;
    const int w = t >> 6;
    const int lane = t & 63;
    const float* M = orb + (size_t)w*4096 + (size_t)lane*64;
    const float ex = expv[w*64 + lane];
    float rr[64];
    #pragma unroll
    for (int j = 0; j < 64; j += 4) {
        float4 v = *reinterpret_cast<const float4*>(M + j);
        rr[j]=v.x*ex; rr[j+1]=v.y*ex; rr[j+2]=v.z*ex; rr[j+3]=v.w*ex;
    }
    float pv_mine = 1.f;
    bool active = true;
    #pragma unroll
    for (int k = 0; k < 64; ++k) {
        int bits = (int)(__float_as_uint(rr[k]) & 0x7FFFFFC0u);
        int v = active ? (bits | lane) : lane;
        int tmp;
        tmp = __builtin_amdgcn_update_dpp(0, v, 0xB1,  0xF, 0xF, true); v = imax2(v, tmp);
        tmp = __builtin_amdgcn_update_dpp(0, v, 0x4E,  0xF, 0xF, true); v = imax2(v, tmp);
        tmp = __builtin_amdgcn_update_dpp(0, v, 0x141, 0xF, 0xF, true); v = imax2(v, tmp);
        tmp = __builtin_amdgcn_update_dpp(0, v, 0x140, 0xF, 0xF, true); v = imax2(v, tmp);
        tmp = __builtin_amdgcn_update_dpp(0, v, 0x142, 0xF, 0xF, true); v = imax2(v, tmp);
        tmp = __builtin_amdgcn_update_dpp(0, v, 0x143, 0xF, 0xF, true); v = imax2(v, tmp);
        const int idx = __builtin_amdgcn_readlane(v, 63) & 63;
        const float piv = readlane_f(rr[k], idx);
        pv_mine = (lane == k) ? piv : pv_mine;
        const float linv = __builtin_amdgcn_rcpf(piv);
        const float l = (active && lane != idx) ? rr[k]*linv : 0.f;
        if (lane == idx) active = false;
        #pragma unroll
        for (int j = k+1; j < 64; ++j)
            rr[j] = fmaf(-l, readlane_f(rr[j], idx), rr[j]);
    }
    float lg = logf(fabsf(pv_mine));
    #pragma unroll
    for (int off = 32; off; off >>= 1) lg += __shfl_down(lg, off);
    if (lane == 0) parts[w] = lg;
    __syncthreads();
    if (t == 0) out[0] = parts[0] + parts[1];
}

// ---------------------------------------------------------------------------
extern "C" void kernel_launch(void* const* d_in, const int* in_sizes, int n_in,
                              void* d_out, int out_size, void* d_ws, size_t ws_size,
                              hipStream_t stream)
{
    const float* r    = (const float*)d_in[0];
    const float* apos = (const float*)d_in[1];
    const float* V0w  = (const float*)d_in[2];
    const float* V0b  = (const float*)d_in[3];
    const float* W0w  = (const float*)d_in[4];
    const float* W0b  = (const float*)d_in[5];
    const float* V1w  = (const float*)d_in[6];
    const float* V1b  = (const float*)d_in[7];
    const float* W1w  = (const float*)d_in[8];
    const float* W1b  = (const float*)d_in[9];
    const float* V2w  = (const float*)d_in[10];
    const float* V2b  = (const float*)d_in[11];
    const float* W2w  = (const float*)d_in[12];
    const float* W2b  = (const float*)d_in[13];
    const float* afw  = (const float*)d_in[14];
    const float* afb  = (const float*)d_in[15];
    const float* vhuw = (const float*)d_in[16];
    const float* vhub = (const float*)d_in[17];
    const float* vhdw = (const float*)d_in[18];
    const float* vhdb = (const float*)d_in[19];
    const float* wuw  = (const float*)d_in[20];
    const float* wub  = (const float*)d_in[21];
    const float* wdw  = (const float*)d_in[22];
    const float* wdb  = (const float*)d_in[23];

    float* ws   = (float*)d_ws;
    float* svA  = ws;              // 65536
    float* svB  = svA  + 65536;    // 65536
    float* expv = svB  + 65536;    // 128
    float* pme1 = expv + 128;      // 16384
    float* pme2 = pme1 + 16384;    // 16384
    float* pme3 = pme2 + 16384;    // 16384
    float* psA  = pme3 + 16384;    // 16384
    float* psB  = psA  + 16384;    // 16384
    float* orb  = psB  + 16384;    // 8192
    float* Cmat = orb  + 8192;     // 2*32768
    float* cb   = Cmat + 65536;    // 128

    // K1: pchain || A0 || headC || cb  (578 independent blocks)
    front_kernel<<<578, 512, 0, stream>>>(r, apos, V0w, V0b, W0w, W0b,
                                          W1w, W1b, W2w, W2b,
                                          vhuw, vhub, vhdw, vhdb,
                                          wuw, wub, wdw, wdb,
                                          svA, expv, pme1, pme2, pme3, psA,
                                          Cmat, cb);
    // K2: A1 (+ orb = cb init role, block 256)
    a2_kernel<512, 64><<<257, 512, 0, stream>>>(svA, pme1, psA, V1w, V1b,
                                                svB, psB, orb, cb);
    // K3: A2
    a2_kernel<512, 64><<<256, 512, 0, stream>>>(svB, pme2, psB, V2w, V2b,
                                                svA, psA, nullptr, nullptr);
    // K4: A3 + heads (atomic C-partials into orb; svB never stored)
    a3h_kernel<<<256, 512, 0, stream>>>(svA, pme3, psA, afw, afb, Cmat, orb);
    // K5: determinants (applies expv row scale)
    det_kernel<<<1, 128, 0, stream>>>(orb, expv, (float*)d_out);
}